// Round 14
// baseline (5360.628 us; speedup 1.0000x reference)
//
#include <hip/hip_runtime.h>
#include <hip/hip_bf16.h>

#define Bsz 256
#define Tlen 512
#define Dd 512
#define Hh 1024
#define G4 4096
#define NOUT 8
#define BT (Bsz * Tlen)

typedef short s16x8 __attribute__((ext_vector_type(8)));
typedef unsigned short u16x8 __attribute__((ext_vector_type(8)));
typedef float f32x4 __attribute__((ext_vector_type(4)));

__device__ __forceinline__ ushort f2bf(float f) {
    union { float f; uint u; } v; v.f = f;
    uint u = v.u;
    uint r = u + 0x7FFFu + ((u >> 16) & 1u);   // round-to-nearest-even
    return (ushort)(r >> 16);
}
__device__ __forceinline__ float bf2f(ushort u) {
    union { uint u; float f; } v; v.u = ((uint)u) << 16; return v.f;
}
__device__ __forceinline__ float sigf(float x) { return 1.f / (1.f + __expf(-x)); }
__device__ __forceinline__ float tanhfast(float x) {
    float ax = fabsf(x);
    float e = __expf(-2.f * ax);
    float t = (1.f - e) / (1.f + e);
    return copysignf(t, x);
}
__device__ __forceinline__ void gload16(const void* g, void* l) {
    __builtin_amdgcn_global_load_lds(
        (const __attribute__((address_space(1))) uint*)g,
        (__attribute__((address_space(3))) uint*)l, 16, 0, 0);
}
// xp element access (bf16 or fp32 tier)
__device__ __forceinline__ void xp_store(ushort* p, float v) { *p = f2bf(v); }
__device__ __forceinline__ void xp_store(float* p, float v) { *p = v; }
__device__ __forceinline__ float xp_load(const ushort* p) { return bf2f(*p); }
__device__ __forceinline__ float xp_load(const float* p) { return *p; }

// ---------------- init: zero h0 (bf16, buffer 0) and c (fp32) ----------------
__global__ void init_kernel(uint4* __restrict__ h0, uint4* __restrict__ c) {
    int i = blockIdx.x * 256 + threadIdx.x;       // 65536 threads
    uint4 z = make_uint4(0u, 0u, 0u, 0u);
    c[i] = z;                                     // 1 MB
    if (i < 32768) h0[i] = z;                     // 512 KB
}

// ---------------- fp32 -> bf16 convert (layout-preserving) ----------------
__global__ void cvt_kernel(const float4* __restrict__ src, ushort4* __restrict__ dst, int n4) {
    int i = blockIdx.x * 256 + threadIdx.x;
    if (i >= n4) return;
    float4 v = src[i];
    ushort4 o;
    o.x = f2bf(v.x); o.y = f2bf(v.y); o.z = f2bf(v.z); o.w = f2bf(v.w);
    dst[i] = o;
}

// ---------------- chunk convert (fallback T3): x[:, t0..t0+7, :] -> [256][8][512] bf16 ----
__global__ void cvt_xchunk(const float* __restrict__ x, ushort* __restrict__ dst, int t0) {
    int gid = blockIdx.x * 256 + threadIdx.x;     // 131072 units of 8 elems
    int k8  = gid & 63;
    int tl  = (gid >> 6) & 7;
    int row = gid >> 9;                           // 0..255
    const float* s = x + ((size_t)row * Tlen + t0 + tl) * Dd + k8 * 8;
    float4 v0 = *(const float4*)s;
    float4 v1 = *(const float4*)(s + 4);
    u16x8 o;
    o[0]=f2bf(v0.x); o[1]=f2bf(v0.y); o[2]=f2bf(v0.z); o[3]=f2bf(v0.w);
    o[4]=f2bf(v1.x); o[5]=f2bf(v1.y); o[6]=f2bf(v1.z); o[7]=f2bf(v1.w);
    *(u16x8*)(dst + ((size_t)row * 8 + tl) * Dd + k8 * 8) = o;
}

// ---------------- x_proj chunk GEMM, all-gload16, CH steps per launch ----------------
// xp[tl][b][g] = xbf[b, t0+tl, :] . Wih[g, :] + b_ih[g] + b_hh[g]
// M = 256*CH (grow = b*CH + tl), N = 4096, K = 512. Tile 128x128, 256 thr
// (4 waves of 64x64), BK=64, dbuf, both operands via gload16 (pre-swizzled src).
// CH>=16: XCD-chunked block remap (bijective since grid%8==0).
template <int LOG2CH>
__launch_bounds__(256)
__global__ void xproj_chunk_bf(const ushort* __restrict__ xbf,
                               const ushort* __restrict__ Wih,
                               const float* __restrict__ b_ih,
                               const float* __restrict__ b_hh,
                               float* __restrict__ xp, int t0) {
    constexpr int CH = 1 << LOG2CH;
    __shared__ ushort As[2][128 * 64];
    __shared__ ushort Bs[2][128 * 64];
    const int tid  = threadIdx.x;
    const int lane = tid & 63;
    const int wid  = tid >> 6;
    const int wr   = wid >> 1;
    const int wc   = wid & 1;
    int eff;
    if constexpr (LOG2CH >= 4) {
        eff = (blockIdx.x & 7) * (gridDim.x >> 3) + (blockIdx.x >> 3);
    } else {
        eff = blockIdx.x;
    }
    const int mt   = eff >> 5;
    const int nt   = eff & 31;
    const int m0   = mt * 128;
    const int n0   = nt * 128;

    f32x4 acc[4][4] = {};

    auto stage = [&](int buf, int kb) {
        const int k0 = kb << 6;
        #pragma unroll
        for (int ii = 0; ii < 4; ++ii) {
            const int inst = (wid << 2) + ii;   // 0..15
            const int r0 = inst << 3;
            const int r  = r0 + (lane >> 3);
            const int sw = ((lane & 7) ^ (r & 7)) << 3;
            const int grow = m0 + r;            // b = grow>>LOG2CH, tl = grow&(CH-1)
            gload16(&xbf[((size_t)(grow >> LOG2CH) * Tlen + t0 + (grow & (CH - 1))) * Dd + k0 + sw],
                    &As[buf][r0 * 64]);
            gload16(&Wih[(size_t)(n0 + r) * Dd + k0 + sw], &Bs[buf][r0 * 64]);
        }
    };
    auto compute = [&](int buf) {
        #pragma unroll
        for (int ks = 0; ks < 2; ++ks) {
            const int kc = (ks << 2) + (lane >> 4);
            s16x8 a[4], b[4];
            #pragma unroll
            for (int m = 0; m < 4; ++m) {
                int row = (wr << 6) + (m << 4) + (lane & 15);
                a[m] = *(const s16x8*)&As[buf][row * 64 + ((kc ^ (row & 7)) << 3)];
            }
            #pragma unroll
            for (int n = 0; n < 4; ++n) {
                int col = (wc << 6) + (n << 4) + (lane & 15);
                b[n] = *(const s16x8*)&Bs[buf][col * 64 + ((kc ^ (col & 7)) << 3)];
            }
            #pragma unroll
            for (int m = 0; m < 4; ++m)
                #pragma unroll
                for (int n = 0; n < 4; ++n)
                    acc[m][n] = __builtin_amdgcn_mfma_f32_16x16x32_bf16(a[m], b[n], acc[m][n], 0, 0, 0);
        }
    };

    stage(0, 0);
    __syncthreads();
    for (int kb = 0; kb < 8; ++kb) {
        if (kb < 7) stage((kb + 1) & 1, kb + 1);
        compute(kb & 1);
        __syncthreads();
    }

    float bias[4];
    #pragma unroll
    for (int n = 0; n < 4; ++n) {
        int gcol = n0 + (wc << 6) + (n << 4) + (lane & 15);
        bias[n] = b_ih[gcol] + b_hh[gcol];
    }
    #pragma unroll
    for (int m = 0; m < 4; ++m)
        #pragma unroll
        for (int n = 0; n < 4; ++n)
            #pragma unroll
            for (int j = 0; j < 4; ++j) {
                int grow = m0 + (wr << 6) + (m << 4) + ((lane >> 4) << 2) + j;
                int gcol = n0 + (wc << 6) + (n << 4) + (lane & 15);
                int b_ = grow >> LOG2CH, tl = grow & (CH - 1);
                xp[((size_t)tl * Bsz + b_) * G4 + gcol] = acc[m][n][j] + bias[n];
            }
}

// ---------------- x_proj chunk GEMM (T2, proven r11): A from fp32 x ----------------
template <typename XT>
__launch_bounds__(256)
__global__ void xproj_chunk(const float* __restrict__ x,
                            const ushort* __restrict__ Wih,
                            const float* __restrict__ b_ih,
                            const float* __restrict__ b_hh,
                            XT* __restrict__ xp, int t0) {
    __shared__ ushort As[2][128 * 64];
    __shared__ ushort Bs[2][128 * 64];
    const int tid  = threadIdx.x;
    const int lane = tid & 63;
    const int wid  = tid >> 6;
    const int wr   = wid >> 1;
    const int wc   = wid & 1;
    const int mt   = blockIdx.x >> 5;   // 0..15
    const int nt   = blockIdx.x & 31;   // 0..31
    const int m0   = mt * 128;
    const int n0   = nt * 128;

    f32x4 acc[4][4] = {};

    auto stageA = [&](int buf, int kb) {
        const int k0 = kb << 6;
        #pragma unroll
        for (int it = 0; it < 8; ++it) {
            int idx = tid + (it << 8);          // 0..2047
            int row = idx >> 4;                 // 0..127
            int k   = (idx & 15) << 2;          // 0..60
            int grow = m0 + row;                // b = grow>>3, tl = grow&7
            const float4 v = *(const float4*)&x[((size_t)(grow >> 3) * Tlen + t0 + (grow & 7)) * Dd + k0 + k];
            ushort4 o;
            o.x = f2bf(v.x); o.y = f2bf(v.y); o.z = f2bf(v.z); o.w = f2bf(v.w);
            int dst = (row << 6) + (((k >> 3) ^ (row & 7)) << 3) + (k & 7);
            *(ushort4*)&As[buf][dst] = o;
        }
    };
    auto stageB = [&](int buf, int kb) {
        const int k0 = kb << 6;
        #pragma unroll
        for (int ii = 0; ii < 4; ++ii) {
            const int inst = (wid << 2) + ii;   // 0..15
            const int r0 = inst << 3;
            const int r  = r0 + (lane >> 3);
            const int sw = ((lane & 7) ^ (r & 7)) << 3;
            gload16(&Wih[(size_t)(n0 + r) * Dd + k0 + sw], &Bs[buf][r0 * 64]);
        }
    };
    auto compute = [&](int buf) {
        #pragma unroll
        for (int ks = 0; ks < 2; ++ks) {
            const int kc = (ks << 2) + (lane >> 4);
            s16x8 a[4], b[4];
            #pragma unroll
            for (int m = 0; m < 4; ++m) {
                int row = (wr << 6) + (m << 4) + (lane & 15);
                a[m] = *(const s16x8*)&As[buf][row * 64 + ((kc ^ (row & 7)) << 3)];
            }
            #pragma unroll
            for (int n = 0; n < 4; ++n) {
                int col = (wc << 6) + (n << 4) + (lane & 15);
                b[n] = *(const s16x8*)&Bs[buf][col * 64 + ((kc ^ (col & 7)) << 3)];
            }
            #pragma unroll
            for (int m = 0; m < 4; ++m)
                #pragma unroll
                for (int n = 0; n < 4; ++n)
                    acc[m][n] = __builtin_amdgcn_mfma_f32_16x16x32_bf16(a[m], b[n], acc[m][n], 0, 0, 0);
        }
    };

    stageB(0, 0); stageA(0, 0);
    __syncthreads();
    for (int kb = 0; kb < 8; ++kb) {
        if (kb < 7) { stageB((kb + 1) & 1, kb + 1); stageA((kb + 1) & 1, kb + 1); }
        compute(kb & 1);
        __syncthreads();
    }

    float bias[4];
    #pragma unroll
    for (int n = 0; n < 4; ++n) {
        int gcol = n0 + (wc << 6) + (n << 4) + (lane & 15);
        bias[n] = b_ih[gcol] + b_hh[gcol];
    }
    #pragma unroll
    for (int m = 0; m < 4; ++m)
        #pragma unroll
        for (int n = 0; n < 4; ++n)
            #pragma unroll
            for (int j = 0; j < 4; ++j) {
                int grow = m0 + (wr << 6) + (m << 4) + ((lane >> 4) << 2) + j;
                int gcol = n0 + (wc << 6) + (n << 4) + (lane & 15);
                int b_ = grow >> 3, tl = grow & 7;
                xp_store(&xp[((size_t)tl * Bsz + b_) * G4 + gcol], acc[m][n][j] + bias[n]);
            }
}

// ---------------- LSTM step, K=1024 recurrent only (r11 structure, proven) ----------------
template <typename XT>
__launch_bounds__(512, 2)
__global__ void lstm_step9(const XT* __restrict__ xp,    // [nT][256][4096] incl. biases
                           int tl,
                           const ushort* __restrict__ Whh,   // bf16 [4096][1024]
                           const ushort* __restrict__ h_prev,// bf16 [256][1024]
                           ushort* __restrict__ h_next,
                           float* __restrict__ c) {          // fp32 [256][1024]
    __shared__ char smem[131072];

    const int tid  = threadIdx.x;
    const int lane = tid & 63;
    const int w    = tid >> 6;
    const int g    = w >> 1;         // K-group 0..3
    const int ab   = w & 1;
    const int B    = blockIdx.x;
    const int xcd  = B & 7, slot = B >> 3;
    const int jt   = xcd * 8 + (slot >> 2);
    const int bt   = slot & 3;
    const int b0   = bt * 64;

    // ---- epilogue prefetch (hidden under the K-loop) ----
    const int erow = tid >> 3;            // 0..63
    const int ecv  = (tid * 2) & 15;      // even
    const size_t cbase = (size_t)(b0 + erow) * Hh + (jt << 4) + ecv;
    const float c0 = c[cbase], c1 = c[cbase + 1];
    const XT* xpr = xp + ((size_t)tl * Bsz + b0 + erow) * G4 + (jt << 4) + ecv;
    float xg[4][2];
    #pragma unroll
    for (int gi = 0; gi < 4; ++gi) {
        xg[gi][0] = xp_load(xpr + gi * Hh);
        xg[gi][1] = xp_load(xpr + gi * Hh + 1);
    }

    f32x4 acc[4][2] = {};

    auto STAGE = [&](int buf, int it) {
        const int k0 = (g << 8) + (it << 6);
        char* base = smem + g * 32768 + buf * 16384 + ab * 8192;
        if (ab == 0) {
            #pragma unroll
            for (int q = 0; q < 8; ++q) {
                int r  = q * 8 + (lane >> 3);
                int cs = (lane & 7) ^ (r & 7);
                gload16(h_prev + (size_t)(b0 + r) * Hh + k0 + cs * 8, base + q * 1024);
            }
        } else {
            #pragma unroll
            for (int q = 0; q < 8; ++q) {
                int col = q * 8 + (lane >> 3);
                int cs  = (lane & 7) ^ (col & 7);
                int grow = ((col >> 4) << 10) + (jt << 4) + (col & 15);
                gload16(Whh + (size_t)grow * Hh + k0 + cs * 8, base + q * 1024);
            }
        }
    };
    auto COMPUTE = [&](int buf) {
        const char* Ab = smem + g * 32768 + buf * 16384;
        const char* Bb = Ab + 8192;
        #pragma unroll
        for (int ks = 0; ks < 2; ++ks) {
            const int kc = (ks << 2) + (lane >> 4);
            s16x8 a[4], bb[2];
            #pragma unroll
            for (int m = 0; m < 4; ++m) {
                int row = (m << 4) + (lane & 15);
                a[m] = *(const s16x8*)(Ab + row * 128 + ((kc ^ (row & 7)) << 4));
            }
            #pragma unroll
            for (int n = 0; n < 2; ++n) {
                int col = (ab << 5) + (n << 4) + (lane & 15);
                bb[n] = *(const s16x8*)(Bb + col * 128 + ((kc ^ (col & 7)) << 4));
            }
            #pragma unroll
            for (int m = 0; m < 4; ++m)
                #pragma unroll
                for (int n = 0; n < 2; ++n)
                    acc[m][n] = __builtin_amdgcn_mfma_f32_16x16x32_bf16(a[m], bb[n], acc[m][n], 0, 0, 0);
        }
    };

    STAGE(0, 0);
    __syncthreads();
    #pragma unroll
    for (int it = 0; it < 4; ++it) {
        if (it < 3) STAGE((it + 1) & 1, it + 1);
        COMPUTE(it & 1);
        __syncthreads();
    }

    // ---- partials: group g -> LDS ----
    float* bw = (float*)smem + g * (64 * 68);
    #pragma unroll
    for (int m = 0; m < 4; ++m)
        #pragma unroll
        for (int n = 0; n < 2; ++n)
            #pragma unroll
            for (int j = 0; j < 4; ++j) {
                int row = (m << 4) + ((lane >> 4) << 2) + j;
                int col = (ab << 5) + (n << 4) + (lane & 15);
                bw[row * 68 + col] = acc[m][n][j];
            }
    __syncthreads();

    // ---- reduce 4 partials + activations + cell update ----
    const float* bufs = (const float*)smem;
    #pragma unroll
    for (int u = 0; u < 2; ++u) {
        const int cv = ecv + u;
        float gi = xg[0][u], gf = xg[1][u], gg = xg[2][u], go = xg[3][u];
        #pragma unroll
        for (int p = 0; p < 4; ++p) {
            const float* bb = bufs + p * (64 * 68) + erow * 68;
            gi += bb[cv]; gf += bb[16 + cv]; gg += bb[32 + cv]; go += bb[48 + cv];
        }
        float i_ = sigf(gi), f_ = sigf(gf), g_ = tanhfast(gg), o_ = sigf(go);
        float cn = f_ * (u ? c1 : c0) + i_ * g_;
        c[cbase + u] = cn;
        h_next[cbase + u] = f2bf(o_ * tanhfast(cn));
    }
}

// ---------------- r4 step kernel (fallback T3, proven 5618 us) ----------------
__launch_bounds__(512, 2)
__global__ void lstm_step3(const ushort* __restrict__ xsrc, int tstride, int tloc,
                           const ushort* __restrict__ Wih,
                           const ushort* __restrict__ Whh,
                           const ushort* __restrict__ h_prev,
                           ushort* __restrict__ h_next,
                           float* __restrict__ c,
                           const float* __restrict__ b_ih,
                           const float* __restrict__ b_hh) {
    __shared__ char smem[131072];
    __shared__ float bias_lds[64];

    const int tid  = threadIdx.x;
    const int lane = tid & 63;
    const int w    = tid >> 6;
    const int g    = w >> 1;
    const int ab   = w & 1;

    const int B   = blockIdx.x;
    const int xcd  = B & 7, slot = B >> 3;
    const int jt   = xcd * 8 + (slot >> 2);
    const int bt   = slot & 3;
    const int b0   = bt * 64;

    if (tid < 64) {
        int gcol = (tid >> 4) * 1024 + jt * 16 + (tid & 15);
        bias_lds[tid] = b_ih[gcol] + b_hh[gcol];
    }

    f32x4 acc[4][2] = {};

    auto STAGE = [&](int buf, int it) {
        const int k0 = (g * 6 + it) << 6;
        char* base = smem + g * 32768 + buf * 16384 + ab * 8192;
        if (ab == 0) {
            if (k0 < Dd) {
                #pragma unroll
                for (int q = 0; q < 8; ++q) {
                    int r  = q * 8 + (lane >> 3);
                    int cs = (lane & 7) ^ (r & 7);
                    const ushort* gp = xsrc + ((size_t)(b0 + r) * tstride + tloc) * Dd + k0 + cs * 8;
                    gload16(gp, base + q * 1024);
                }
            } else {
                #pragma unroll
                for (int q = 0; q < 8; ++q) {
                    int r  = q * 8 + (lane >> 3);
                    int cs = (lane & 7) ^ (r & 7);
                    const ushort* gp = h_prev + (size_t)(b0 + r) * Hh + (k0 - Dd) + cs * 8;
                    gload16(gp, base + q * 1024);
                }
            }
        } else {
            #pragma unroll
            for (int q = 0; q < 8; ++q) {
                int col = q * 8 + (lane >> 3);
                int cs  = (lane & 7) ^ (col & 7);
                int grow = (col >> 4) * 1024 + jt * 16 + (col & 15);
                const ushort* gp = (k0 < Dd)
                    ? (Wih + (size_t)grow * Dd + k0 + cs * 8)
                    : (Whh + (size_t)grow * Hh + (k0 - Dd) + cs * 8);
                gload16(gp, base + q * 1024);
            }
        }
    };
    auto COMPUTE = [&](int buf) {
        const char* Ab = smem + g * 32768 + buf * 16384;
        const char* Bb = Ab + 8192;
        #pragma unroll
        for (int ks = 0; ks < 2; ++ks) {
            const int kc = (ks << 2) + (lane >> 4);
            s16x8 a[4], bb[2];
            #pragma unroll
            for (int m = 0; m < 4; ++m) {
                int row = (m << 4) + (lane & 15);
                a[m] = *(const s16x8*)(Ab + row * 128 + ((kc ^ (row & 7)) << 4));
            }
            #pragma unroll
            for (int n = 0; n < 2; ++n) {
                int col = (ab << 5) + (n << 4) + (lane & 15);
                bb[n] = *(const s16x8*)(Bb + col * 128 + ((kc ^ (col & 7)) << 4));
            }
            #pragma unroll
            for (int m = 0; m < 4; ++m)
                #pragma unroll
                for (int n = 0; n < 2; ++n)
                    acc[m][n] = __builtin_amdgcn_mfma_f32_16x16x32_bf16(a[m], bb[n], acc[m][n], 0, 0, 0);
        }
    };

    STAGE(0, 0);
    __syncthreads();
    #pragma unroll
    for (int it = 0; it < 6; ++it) {
        if (it < 5) STAGE((it + 1) & 1, it + 1);
        COMPUTE(it & 1);
        __syncthreads();
    }

    float* bw = (float*)smem + g * (64 * 68);
    #pragma unroll
    for (int m = 0; m < 4; ++m)
        #pragma unroll
        for (int n = 0; n < 2; ++n)
            #pragma unroll
            for (int j = 0; j < 4; ++j) {
                int row = (m << 4) + ((lane >> 4) << 2) + j;
                int col = (ab << 5) + (n << 4) + (lane & 15);
                bw[row * 68 + col] = acc[m][n][j];
            }
    __syncthreads();

    const float* bufs = (const float*)smem;
    #pragma unroll
    for (int u = 0; u < 2; ++u) {
        int cell = tid * 2 + u;
        int row  = cell >> 4;
        int cv   = cell & 15;
        float gi = 0.f, gf = 0.f, gg = 0.f, go = 0.f;
        #pragma unroll
        for (int p = 0; p < 4; ++p) {
            const float* bb = bufs + p * (64 * 68) + row * 68;
            gi += bb[cv]; gf += bb[16 + cv]; gg += bb[32 + cv]; go += bb[48 + cv];
        }
        gi += bias_lds[cv];      gf += bias_lds[16 + cv];
        gg += bias_lds[32 + cv]; go += bias_lds[48 + cv];
        float i_ = sigf(gi), f_ = sigf(gf), g_ = tanhfast(gg), o_ = sigf(go);
        int gcol = jt * 16 + cv;
        size_t cidx = (size_t)(b0 + row) * Hh + gcol;
        float cn = f_ * c[cidx] + i_ * g_;
        c[cidx] = cn;
        h_next[cidx] = f2bf(o_ * tanhfast(cn));
    }
}

// ---------------- T4 fallback (proven round-0) ----------------
__launch_bounds__(256)
__global__ void lstm_step_fused(const float* __restrict__ x,
                          const ushort* __restrict__ Wih,
                          const ushort* __restrict__ Whh,
                          const float* __restrict__ b_ih,
                          const float* __restrict__ b_hh,
                          const ushort* __restrict__ h_prev,
                          ushort* __restrict__ h_next,
                          float* __restrict__ c,
                          int t) {
    __shared__ ushort At[64 * 64];
    __shared__ ushort Bt[64 * 64];
    __shared__ float gates[64 * 72];

    const int tid  = threadIdx.x;
    const int lane = tid & 63;
    const int wid  = tid >> 6;
    const int wr   = wid >> 1;
    const int wc   = wid & 1;
    const int bt   = blockIdx.x >> 6;
    const int jt   = blockIdx.x & 63;
    const int b0   = bt * 64;
    const int j0   = jt * 16;

    f32x4 acc[2][2] = {};

    auto mfma_tile = [&]() {
        #pragma unroll
        for (int ks = 0; ks < 2; ++ks) {
            const int kc = (ks << 2) + (lane >> 4);
            s16x8 a[2], bfr[2];
            #pragma unroll
            for (int m = 0; m < 2; ++m) {
                int row = wr * 32 + m * 16 + (lane & 15);
                a[m] = *(const s16x8*)&At[row * 64 + ((kc ^ (row & 7)) << 3)];
            }
            #pragma unroll
            for (int n = 0; n < 2; ++n) {
                int col = wc * 32 + n * 16 + (lane & 15);
                bfr[n] = *(const s16x8*)&Bt[col * 64 + ((kc ^ (col & 7)) << 3)];
            }
            #pragma unroll
            for (int m = 0; m < 2; ++m)
                #pragma unroll
                for (int n = 0; n < 2; ++n)
                    acc[m][n] = __builtin_amdgcn_mfma_f32_16x16x32_bf16(a[m], bfr[n], acc[m][n], 0, 0, 0);
        }
    };

    for (int kb = 0; kb < Dd; kb += 64) {
        __syncthreads();
        #pragma unroll
        for (int it = 0; it < 4; ++it) {
            int idx = tid + it * 256;
            int row = idx >> 4;
            int k   = (idx & 15) * 4;
            const float4 v = *(const float4*)&x[(size_t)(b0 + row) * (Tlen * Dd) + (size_t)t * Dd + kb + k];
            ushort4 o;
            o.x = f2bf(v.x); o.y = f2bf(v.y); o.z = f2bf(v.z); o.w = f2bf(v.w);
            int dst = row * 64 + (((k >> 3) ^ (row & 7)) << 3) + (k & 7);
            *(ushort4*)&At[dst] = o;
        }
        #pragma unroll
        for (int it = 0; it < 2; ++it) {
            int idx = tid + it * 256;
            int col = idx >> 3;
            int kc  = idx & 7;
            int grow = ((col >> 4) << 10) + j0 + (col & 15);
            uint4 v = *(const uint4*)&Wih[(size_t)grow * Dd + kb + kc * 8];
            *(uint4*)&Bt[col * 64 + ((kc ^ (col & 7)) << 3)] = v;
        }
        __syncthreads();
        mfma_tile();
    }
    for (int kb = 0; kb < Hh; kb += 64) {
        __syncthreads();
        #pragma unroll
        for (int it = 0; it < 2; ++it) {
            int idx = tid + it * 256;
            int row = idx >> 3;
            int kc  = idx & 7;
            uint4 v = *(const uint4*)&h_prev[(size_t)(b0 + row) * Hh + kb + kc * 8];
            *(uint4*)&At[row * 64 + ((kc ^ (row & 7)) << 3)] = v;
        }
        #pragma unroll
        for (int it = 0; it < 2; ++it) {
            int idx = tid + it * 256;
            int col = idx >> 3;
            int kc  = idx & 7;
            int grow = ((col >> 4) << 10) + j0 + (col & 15);
            uint4 v = *(const uint4*)&Whh[(size_t)grow * Hh + kb + kc * 8];
            *(uint4*)&Bt[col * 64 + ((kc ^ (col & 7)) << 3)] = v;
        }
        __syncthreads();
        mfma_tile();
    }

    #pragma unroll
    for (int m = 0; m < 2; ++m)
        #pragma unroll
        for (int n = 0; n < 2; ++n)
            #pragma unroll
            for (int j = 0; j < 4; ++j) {
                int row = wr * 32 + m * 16 + ((lane >> 4) << 2) + j;
                int col = wc * 32 + n * 16 + (lane & 15);
                gates[row * 72 + col] = acc[m][n][j];
            }
    __syncthreads();

    #pragma unroll
    for (int it = 0; it < 4; ++it) {
        int idx = tid + it * 256;
        int row = idx >> 4;
        int cc  = idx & 15;
        int gcol = j0 + cc;
        float gi = gates[row * 72 + cc]      + b_ih[gcol]          + b_hh[gcol];
        float gf = gates[row * 72 + 16 + cc] + b_ih[Hh + gcol]     + b_hh[Hh + gcol];
        float gg = gates[row * 72 + 32 + cc] + b_ih[2 * Hh + gcol] + b_hh[2 * Hh + gcol];
        float go = gates[row * 72 + 48 + cc] + b_ih[3 * Hh + gcol] + b_hh[3 * Hh + gcol];
        float i_ = sigf(gi);
        float f_ = sigf(gf);
        float g_ = tanhfast(gg);
        float o_ = sigf(go);
        size_t cidx = (size_t)(b0 + row) * Hh + gcol;
        float cn = f_ * c[cidx] + i_ * g_;
        c[cidx] = cn;
        float hn = o_ * tanhfast(cn);
        h_next[cidx] = f2bf(hn);
    }
}

// ---------------- FC head ----------------
__global__ void fc_kernel(const ushort* __restrict__ h,
                          const float* __restrict__ Wfc,
                          const float* __restrict__ bfc,
                          float* __restrict__ out) {
    int b = blockIdx.x;
    int w = threadIdx.x >> 6;
    int lane = threadIdx.x & 63;
    float s = 0.f;
    for (int k = lane; k < Hh; k += 64)
        s += bf2f(h[(size_t)b * Hh + k]) * Wfc[w * Hh + k];
    #pragma unroll
    for (int off = 32; off; off >>= 1) s += __shfl_down(s, off);
    if (lane == 0) out[b * NOUT + w] = sigf(s + bfc[w]);
}

// ================= LAUNCH =================

extern "C" void kernel_launch(void* const* d_in, const int* in_sizes, int n_in,
                              void* d_out, int out_size, void* d_ws, size_t ws_size,
                              hipStream_t stream) {
    const float* x    = (const float*)d_in[0];
    const float* W_ih = (const float*)d_in[1];
    const float* W_hh = (const float*)d_in[2];
    const float* b_ih = (const float*)d_in[3];
    const float* b_hh = (const float*)d_in[4];
    const float* W_fc = (const float*)d_in[5];
    const float* b_fc = (const float*)d_in[6];
    float* out = (float*)d_out;
    char* ws = (char*)d_ws;

    // ws layout:
    //   [0, 1 MB)    h ping-pong bf16 [2][256][1024]
    //   [1, 2 MB)    c fp32 [256][1024]
    //   [2, 6 MB)    W_ih bf16 [4096][512]
    //   [6, 14 MB)   W_hh bf16 [4096][1024]
    //   [14 MB, ..)  T1-32: x_bf (128 MB) + xp fp32 CH=32 (134 MB) = 276 MB
    //                T1-16: x_bf (128 MB) + xp fp32 CH=16 (67 MB)  = 209 MB
    //                T1-8 : x_bf (128 MB) + xp fp32 CH=8  (34 MB)  = 175 MB (proven r12)
    //                T2   : xp fp32 ring 2 x 32 MB = 78 MB (proven r11)
    //                T3   : x bf16 chunks 2 x 2 MB (proven r4)
    ushort* h_buf  = (ushort*)ws;
    float*  c_ws   = (float*)(ws + (1ull << 20));
    ushort* wih_bf = (ushort*)(ws + (2ull << 20));
    ushort* whh_bf = (ushort*)(ws + (6ull << 20));
    char*   x_ext  = ws + (14ull << 20);

    const size_t FIXED  = 14ull << 20;
    const size_t XFULL  = (size_t)Bsz * Tlen * Dd * 2;         // 128 MB
    const size_t XP8    = (size_t)8 * Bsz * G4;                // elems
    const size_t XCHUNK = (size_t)Bsz * 8 * Dd * 2;            // 2 MB

    auto xp_need = [&](int ch) { return FIXED + XFULL + (size_t)ch * Bsz * G4 * 4; };

    init_kernel<<<256, 256, 0, stream>>>((uint4*)h_buf, (uint4*)c_ws);
    cvt_kernel<<<(G4 * Dd / 4) / 256, 256, 0, stream>>>((const float4*)W_ih, (ushort4*)wih_bf, G4 * Dd / 4);
    cvt_kernel<<<(G4 * Hh / 4) / 256, 256, 0, stream>>>((const float4*)W_hh, (ushort4*)whh_bf, G4 * Hh / 4);

    if (ws_size >= xp_need(8)) {
        // main path: full x->bf16 once, CH-step chunk GEMMs (largest CH that fits)
        ushort* x_bf = (ushort*)x_ext;
        float*  xpb  = (float*)(x_ext + XFULL);
        const int n4 = BT * Dd / 4;
        cvt_kernel<<<n4 / 256, 256, 0, stream>>>((const float4*)x, (ushort4*)x_bf, n4);
        if (ws_size >= xp_need(32)) {
            for (int t = 0; t < Tlen; ++t) {
                if ((t & 31) == 0)
                    xproj_chunk_bf<5><<<2048, 256, 0, stream>>>(x_bf, wih_bf, b_ih, b_hh, xpb, t);
                const ushort* hp = h_buf + (size_t)(t & 1) * Bsz * Hh;
                ushort*       hn = h_buf + (size_t)((t + 1) & 1) * Bsz * Hh;
                lstm_step9<float><<<256, 512, 0, stream>>>(xpb, t & 31, whh_bf, hp, hn, c_ws);
            }
        } else if (ws_size >= xp_need(16)) {
            for (int t = 0; t < Tlen; ++t) {
                if ((t & 15) == 0)
                    xproj_chunk_bf<4><<<1024, 256, 0, stream>>>(x_bf, wih_bf, b_ih, b_hh, xpb, t);
                const ushort* hp = h_buf + (size_t)(t & 1) * Bsz * Hh;
                ushort*       hn = h_buf + (size_t)((t + 1) & 1) * Bsz * Hh;
                lstm_step9<float><<<256, 512, 0, stream>>>(xpb, t & 15, whh_bf, hp, hn, c_ws);
            }
        } else {
            // exact r12 path (proven 5223 us)
            for (int t = 0; t < Tlen; ++t) {
                if ((t & 7) == 0)
                    xproj_chunk_bf<3><<<512, 256, 0, stream>>>(x_bf, wih_bf, b_ih, b_hh, xpb, t);
                const ushort* hp = h_buf + (size_t)(t & 1) * Bsz * Hh;
                ushort*       hn = h_buf + (size_t)((t + 1) & 1) * Bsz * Hh;
                lstm_step9<float><<<256, 512, 0, stream>>>(xpb, t & 7, whh_bf, hp, hn, c_ws);
            }
        }
    } else if (ws_size >= FIXED + 2 * XP8 * 4) {
        // T2: proven r11 path (5331 us)
        float* xpb0 = (float*)x_ext;
        float* xpb1 = xpb0 + XP8;
        for (int t = 0; t < Tlen; ++t) {
            float* xpb = ((t >> 3) & 1) ? xpb1 : xpb0;
            if ((t & 7) == 0)
                xproj_chunk<float><<<512, 256, 0, stream>>>(x, wih_bf, b_ih, b_hh, xpb, t);
            const ushort* hp = h_buf + (size_t)(t & 1) * Bsz * Hh;
            ushort*       hn = h_buf + (size_t)((t + 1) & 1) * Bsz * Hh;
            lstm_step9<float><<<256, 512, 0, stream>>>(xpb, t & 7, whh_bf, hp, hn, c_ws);
        }
    } else if (ws_size >= FIXED + 2 * XCHUNK) {
        // T3: r4 chunked path (proven 5618 us)
        ushort* xchunk = (ushort*)x_ext;
        for (int t = 0; t < Tlen; ++t) {
            if ((t & 7) == 0) {
                ushort* dst = xchunk + (size_t)((t >> 3) & 1) * (Bsz * 8 * Dd);
                cvt_xchunk<<<512, 256, 0, stream>>>(x, dst, t);
            }
            const ushort* xb = xchunk + (size_t)((t >> 3) & 1) * (Bsz * 8 * Dd);
            const ushort* hp = h_buf + (size_t)(t & 1) * Bsz * Hh;
            ushort*       hn = h_buf + (size_t)((t + 1) & 1) * Bsz * Hh;
            lstm_step3<<<256, 512, 0, stream>>>(xb, 8, t & 7, wih_bf, whh_bf,
                                                hp, hn, c_ws, b_ih, b_hh);
        }
    } else {
        // T4: proven round-0 fallback
        for (int t = 0; t < Tlen; ++t) {
            const ushort* hp = h_buf + (size_t)(t & 1) * Bsz * Hh;
            ushort*       hn = h_buf + (size_t)((t + 1) & 1) * Bsz * Hh;
            lstm_step_fused<<<256, 256, 0, stream>>>(x, wih_bf, whh_bf, b_ih, b_hh, hp, hn, c_ws, t);
        }
    }
    // 512 steps (even) -> final h in buffer 0
    fc_kernel<<<256, 512, 0, stream>>>(h_buf, W_fc, b_fc, out);
}

// Round 15
// 5164.231 us; speedup vs baseline: 1.0380x; 1.0380x over previous
//
#include <hip/hip_runtime.h>
#include <hip/hip_bf16.h>

#define Bsz 256
#define Tlen 512
#define Dd 512
#define Hh 1024
#define G4 4096
#define NOUT 8
#define BT (Bsz * Tlen)

typedef short s16x8 __attribute__((ext_vector_type(8)));
typedef unsigned short u16x8 __attribute__((ext_vector_type(8)));
typedef float f32x4 __attribute__((ext_vector_type(4)));

__device__ __forceinline__ ushort f2bf(float f) {
    union { float f; uint u; } v; v.f = f;
    uint u = v.u;
    uint r = u + 0x7FFFu + ((u >> 16) & 1u);   // round-to-nearest-even
    return (ushort)(r >> 16);
}
__device__ __forceinline__ float bf2f(ushort u) {
    union { uint u; float f; } v; v.u = ((uint)u) << 16; return v.f;
}
__device__ __forceinline__ float sigf(float x) { return 1.f / (1.f + __expf(-x)); }
__device__ __forceinline__ float tanhfast(float x) {
    float ax = fabsf(x);
    float e = __expf(-2.f * ax);
    float t = (1.f - e) / (1.f + e);
    return copysignf(t, x);
}
__device__ __forceinline__ void gload16(const void* g, void* l) {
    __builtin_amdgcn_global_load_lds(
        (const __attribute__((address_space(1))) uint*)g,
        (__attribute__((address_space(3))) uint*)l, 16, 0, 0);
}
// xp element access (bf16 or fp32 tier)
__device__ __forceinline__ void xp_store(ushort* p, float v) { *p = f2bf(v); }
__device__ __forceinline__ void xp_store(float* p, float v) { *p = v; }
__device__ __forceinline__ float xp_load(const ushort* p) { return bf2f(*p); }
__device__ __forceinline__ float xp_load(const float* p) { return *p; }

// ---------------- init: zero h0 (bf16, buffer 0) and c (fp32) ----------------
__global__ void init_kernel(uint4* __restrict__ h0, uint4* __restrict__ c) {
    int i = blockIdx.x * 256 + threadIdx.x;       // 65536 threads
    uint4 z = make_uint4(0u, 0u, 0u, 0u);
    c[i] = z;                                     // 1 MB
    if (i < 32768) h0[i] = z;                     // 512 KB
}

// ---------------- fp32 -> bf16 convert (layout-preserving) ----------------
__global__ void cvt_kernel(const float4* __restrict__ src, ushort4* __restrict__ dst, int n4) {
    int i = blockIdx.x * 256 + threadIdx.x;
    if (i >= n4) return;
    float4 v = src[i];
    ushort4 o;
    o.x = f2bf(v.x); o.y = f2bf(v.y); o.z = f2bf(v.z); o.w = f2bf(v.w);
    dst[i] = o;
}

// ---------------- chunk convert (fallback T3): x[:, t0..t0+7, :] -> [256][8][512] bf16 ----
__global__ void cvt_xchunk(const float* __restrict__ x, ushort* __restrict__ dst, int t0) {
    int gid = blockIdx.x * 256 + threadIdx.x;     // 131072 units of 8 elems
    int k8  = gid & 63;
    int tl  = (gid >> 6) & 7;
    int row = gid >> 9;                           // 0..255
    const float* s = x + ((size_t)row * Tlen + t0 + tl) * Dd + k8 * 8;
    float4 v0 = *(const float4*)s;
    float4 v1 = *(const float4*)(s + 4);
    u16x8 o;
    o[0]=f2bf(v0.x); o[1]=f2bf(v0.y); o[2]=f2bf(v0.z); o[3]=f2bf(v0.w);
    o[4]=f2bf(v1.x); o[5]=f2bf(v1.y); o[6]=f2bf(v1.z); o[7]=f2bf(v1.w);
    *(u16x8*)(dst + ((size_t)row * 8 + tl) * Dd + k8 * 8) = o;
}

// ---------------- x_proj chunk GEMM, all-gload16, 8 steps per launch (proven r12) ----------------
// xp[tl][b][g] = xbf[b, t0+tl, :] . Wih[g, :] + b_ih[g] + b_hh[g]
// M = 2048 (grow = b*8+tl), N = 4096, K = 512. Tile 128x128, 256 thr
// (4 waves of 64x64), BK=64, dbuf, both operands via gload16 (pre-swizzled src).
__launch_bounds__(256)
__global__ void xproj_chunk_bf(const ushort* __restrict__ xbf,
                               const ushort* __restrict__ Wih,
                               const float* __restrict__ b_ih,
                               const float* __restrict__ b_hh,
                               float* __restrict__ xp, int t0) {
    __shared__ ushort As[2][128 * 64];
    __shared__ ushort Bs[2][128 * 64];
    const int tid  = threadIdx.x;
    const int lane = tid & 63;
    const int wid  = tid >> 6;
    const int wr   = wid >> 1;
    const int wc   = wid & 1;
    const int mt   = blockIdx.x >> 5;   // 0..15
    const int nt   = blockIdx.x & 31;   // 0..31
    const int m0   = mt * 128;
    const int n0   = nt * 128;

    f32x4 acc[4][4] = {};

    auto stage = [&](int buf, int kb) {
        const int k0 = kb << 6;
        #pragma unroll
        for (int ii = 0; ii < 4; ++ii) {
            const int inst = (wid << 2) + ii;   // 0..15
            const int r0 = inst << 3;
            const int r  = r0 + (lane >> 3);
            const int sw = ((lane & 7) ^ (r & 7)) << 3;
            const int grow = m0 + r;            // b = grow>>3, tl = grow&7
            gload16(&xbf[((size_t)(grow >> 3) * Tlen + t0 + (grow & 7)) * Dd + k0 + sw],
                    &As[buf][r0 * 64]);
            gload16(&Wih[(size_t)(n0 + r) * Dd + k0 + sw], &Bs[buf][r0 * 64]);
        }
    };
    auto compute = [&](int buf) {
        #pragma unroll
        for (int ks = 0; ks < 2; ++ks) {
            const int kc = (ks << 2) + (lane >> 4);
            s16x8 a[4], b[4];
            #pragma unroll
            for (int m = 0; m < 4; ++m) {
                int row = (wr << 6) + (m << 4) + (lane & 15);
                a[m] = *(const s16x8*)&As[buf][row * 64 + ((kc ^ (row & 7)) << 3)];
            }
            #pragma unroll
            for (int n = 0; n < 4; ++n) {
                int col = (wc << 6) + (n << 4) + (lane & 15);
                b[n] = *(const s16x8*)&Bs[buf][col * 64 + ((kc ^ (col & 7)) << 3)];
            }
            #pragma unroll
            for (int m = 0; m < 4; ++m)
                #pragma unroll
                for (int n = 0; n < 4; ++n)
                    acc[m][n] = __builtin_amdgcn_mfma_f32_16x16x32_bf16(a[m], b[n], acc[m][n], 0, 0, 0);
        }
    };

    stage(0, 0);
    __syncthreads();
    for (int kb = 0; kb < 8; ++kb) {
        if (kb < 7) stage((kb + 1) & 1, kb + 1);
        compute(kb & 1);
        __syncthreads();
    }

    float bias[4];
    #pragma unroll
    for (int n = 0; n < 4; ++n) {
        int gcol = n0 + (wc << 6) + (n << 4) + (lane & 15);
        bias[n] = b_ih[gcol] + b_hh[gcol];
    }
    #pragma unroll
    for (int m = 0; m < 4; ++m)
        #pragma unroll
        for (int n = 0; n < 4; ++n)
            #pragma unroll
            for (int j = 0; j < 4; ++j) {
                int grow = m0 + (wr << 6) + (m << 4) + ((lane >> 4) << 2) + j;
                int gcol = n0 + (wc << 6) + (n << 4) + (lane & 15);
                int b_ = grow >> 3, tl = grow & 7;
                xp[((size_t)tl * Bsz + b_) * G4 + gcol] = acc[m][n][j] + bias[n];
            }
}

// ---------------- x_proj chunk GEMM (T2, proven r11): A from fp32 x ----------------
template <typename XT>
__launch_bounds__(256)
__global__ void xproj_chunk(const float* __restrict__ x,
                            const ushort* __restrict__ Wih,
                            const float* __restrict__ b_ih,
                            const float* __restrict__ b_hh,
                            XT* __restrict__ xp, int t0) {
    __shared__ ushort As[2][128 * 64];
    __shared__ ushort Bs[2][128 * 64];
    const int tid  = threadIdx.x;
    const int lane = tid & 63;
    const int wid  = tid >> 6;
    const int wr   = wid >> 1;
    const int wc   = wid & 1;
    const int mt   = blockIdx.x >> 5;   // 0..15
    const int nt   = blockIdx.x & 31;   // 0..31
    const int m0   = mt * 128;
    const int n0   = nt * 128;

    f32x4 acc[4][4] = {};

    auto stageA = [&](int buf, int kb) {
        const int k0 = kb << 6;
        #pragma unroll
        for (int it = 0; it < 8; ++it) {
            int idx = tid + (it << 8);          // 0..2047
            int row = idx >> 4;                 // 0..127
            int k   = (idx & 15) << 2;          // 0..60
            int grow = m0 + row;                // b = grow>>3, tl = grow&7
            const float4 v = *(const float4*)&x[((size_t)(grow >> 3) * Tlen + t0 + (grow & 7)) * Dd + k0 + k];
            ushort4 o;
            o.x = f2bf(v.x); o.y = f2bf(v.y); o.z = f2bf(v.z); o.w = f2bf(v.w);
            int dst = (row << 6) + (((k >> 3) ^ (row & 7)) << 3) + (k & 7);
            *(ushort4*)&As[buf][dst] = o;
        }
    };
    auto stageB = [&](int buf, int kb) {
        const int k0 = kb << 6;
        #pragma unroll
        for (int ii = 0; ii < 4; ++ii) {
            const int inst = (wid << 2) + ii;   // 0..15
            const int r0 = inst << 3;
            const int r  = r0 + (lane >> 3);
            const int sw = ((lane & 7) ^ (r & 7)) << 3;
            gload16(&Wih[(size_t)(n0 + r) * Dd + k0 + sw], &Bs[buf][r0 * 64]);
        }
    };
    auto compute = [&](int buf) {
        #pragma unroll
        for (int ks = 0; ks < 2; ++ks) {
            const int kc = (ks << 2) + (lane >> 4);
            s16x8 a[4], b[4];
            #pragma unroll
            for (int m = 0; m < 4; ++m) {
                int row = (wr << 6) + (m << 4) + (lane & 15);
                a[m] = *(const s16x8*)&As[buf][row * 64 + ((kc ^ (row & 7)) << 3)];
            }
            #pragma unroll
            for (int n = 0; n < 4; ++n) {
                int col = (wc << 6) + (n << 4) + (lane & 15);
                b[n] = *(const s16x8*)&Bs[buf][col * 64 + ((kc ^ (col & 7)) << 3)];
            }
            #pragma unroll
            for (int m = 0; m < 4; ++m)
                #pragma unroll
                for (int n = 0; n < 4; ++n)
                    acc[m][n] = __builtin_amdgcn_mfma_f32_16x16x32_bf16(a[m], b[n], acc[m][n], 0, 0, 0);
        }
    };

    stageB(0, 0); stageA(0, 0);
    __syncthreads();
    for (int kb = 0; kb < 8; ++kb) {
        if (kb < 7) { stageB((kb + 1) & 1, kb + 1); stageA((kb + 1) & 1, kb + 1); }
        compute(kb & 1);
        __syncthreads();
    }

    float bias[4];
    #pragma unroll
    for (int n = 0; n < 4; ++n) {
        int gcol = n0 + (wc << 6) + (n << 4) + (lane & 15);
        bias[n] = b_ih[gcol] + b_hh[gcol];
    }
    #pragma unroll
    for (int m = 0; m < 4; ++m)
        #pragma unroll
        for (int n = 0; n < 4; ++n)
            #pragma unroll
            for (int j = 0; j < 4; ++j) {
                int grow = m0 + (wr << 6) + (m << 4) + ((lane >> 4) << 2) + j;
                int gcol = n0 + (wc << 6) + (n << 4) + (lane & 15);
                int b_ = grow >> 3, tl = grow & 7;
                xp_store(&xp[((size_t)tl * Bsz + b_) * G4 + gcol], acc[m][n][j] + bias[n]);
            }
}

// ---------------- LSTM step, K=1024 recurrent only (r11 structure + stage-first) ----------------
template <typename XT>
__launch_bounds__(512, 2)
__global__ void lstm_step9(const XT* __restrict__ xp,    // [8][256][4096] chunk incl. biases
                           int tl,
                           const ushort* __restrict__ Whh,   // bf16 [4096][1024]
                           const ushort* __restrict__ h_prev,// bf16 [256][1024]
                           ushort* __restrict__ h_next,
                           float* __restrict__ c) {          // fp32 [256][1024]
    __shared__ char smem[131072];

    const int tid  = threadIdx.x;
    const int lane = tid & 63;
    const int w    = tid >> 6;
    const int g    = w >> 1;         // K-group 0..3
    const int ab   = w & 1;
    const int B    = blockIdx.x;
    const int xcd  = B & 7, slot = B >> 3;
    const int jt   = xcd * 8 + (slot >> 2);
    const int bt   = slot & 3;
    const int b0   = bt * 64;

    auto STAGE = [&](int buf, int it) {
        const int k0 = (g << 8) + (it << 6);
        char* base = smem + g * 32768 + buf * 16384 + ab * 8192;
        if (ab == 0) {
            #pragma unroll
            for (int q = 0; q < 8; ++q) {
                int r  = q * 8 + (lane >> 3);
                int cs = (lane & 7) ^ (r & 7);
                gload16(h_prev + (size_t)(b0 + r) * Hh + k0 + cs * 8, base + q * 1024);
            }
        } else {
            #pragma unroll
            for (int q = 0; q < 8; ++q) {
                int col = q * 8 + (lane >> 3);
                int cs  = (lane & 7) ^ (col & 7);
                int grow = ((col >> 4) << 10) + (jt << 4) + (col & 15);
                gload16(Whh + (size_t)grow * Hh + k0 + cs * 8, base + q * 1024);
            }
        }
    };

    // ---- critical-path staging first: round 0 loads enter the VMEM queue
    // before the epilogue prefetch (which isn't needed for ~5 us).
    STAGE(0, 0);

    // ---- epilogue prefetch (hidden under the K-loop) ----
    const int erow = tid >> 3;            // 0..63
    const int ecv  = (tid * 2) & 15;      // even
    const size_t cbase = (size_t)(b0 + erow) * Hh + (jt << 4) + ecv;
    const float c0 = c[cbase], c1 = c[cbase + 1];
    const XT* xpr = xp + ((size_t)tl * Bsz + b0 + erow) * G4 + (jt << 4) + ecv;
    float xg[4][2];
    #pragma unroll
    for (int gi = 0; gi < 4; ++gi) {
        xg[gi][0] = xp_load(xpr + gi * Hh);
        xg[gi][1] = xp_load(xpr + gi * Hh + 1);
    }

    f32x4 acc[4][2] = {};

    auto COMPUTE = [&](int buf) {
        const char* Ab = smem + g * 32768 + buf * 16384;
        const char* Bb = Ab + 8192;
        #pragma unroll
        for (int ks = 0; ks < 2; ++ks) {
            const int kc = (ks << 2) + (lane >> 4);
            s16x8 a[4], bb[2];
            #pragma unroll
            for (int m = 0; m < 4; ++m) {
                int row = (m << 4) + (lane & 15);
                a[m] = *(const s16x8*)(Ab + row * 128 + ((kc ^ (row & 7)) << 4));
            }
            #pragma unroll
            for (int n = 0; n < 2; ++n) {
                int col = (ab << 5) + (n << 4) + (lane & 15);
                bb[n] = *(const s16x8*)(Bb + col * 128 + ((kc ^ (col & 7)) << 4));
            }
            #pragma unroll
            for (int m = 0; m < 4; ++m)
                #pragma unroll
                for (int n = 0; n < 2; ++n)
                    acc[m][n] = __builtin_amdgcn_mfma_f32_16x16x32_bf16(a[m], bb[n], acc[m][n], 0, 0, 0);
        }
    };

    __syncthreads();
    #pragma unroll
    for (int it = 0; it < 4; ++it) {
        if (it < 3) STAGE((it + 1) & 1, it + 1);
        COMPUTE(it & 1);
        __syncthreads();
    }

    // ---- partials: group g -> LDS ----
    float* bw = (float*)smem + g * (64 * 68);
    #pragma unroll
    for (int m = 0; m < 4; ++m)
        #pragma unroll
        for (int n = 0; n < 2; ++n)
            #pragma unroll
            for (int j = 0; j < 4; ++j) {
                int row = (m << 4) + ((lane >> 4) << 2) + j;
                int col = (ab << 5) + (n << 4) + (lane & 15);
                bw[row * 68 + col] = acc[m][n][j];
            }
    __syncthreads();

    // ---- reduce 4 partials + activations + cell update ----
    const float* bufs = (const float*)smem;
    #pragma unroll
    for (int u = 0; u < 2; ++u) {
        const int cv = ecv + u;
        float gi = xg[0][u], gf = xg[1][u], gg = xg[2][u], go = xg[3][u];
        #pragma unroll
        for (int p = 0; p < 4; ++p) {
            const float* bb = bufs + p * (64 * 68) + erow * 68;
            gi += bb[cv]; gf += bb[16 + cv]; gg += bb[32 + cv]; go += bb[48 + cv];
        }
        float i_ = sigf(gi), f_ = sigf(gf), g_ = tanhfast(gg), o_ = sigf(go);
        float cn = f_ * (u ? c1 : c0) + i_ * g_;
        c[cbase + u] = cn;
        h_next[cbase + u] = f2bf(o_ * tanhfast(cn));
    }
}

// ---------------- r4 step kernel (fallback T3, proven 5618 us) ----------------
__launch_bounds__(512, 2)
__global__ void lstm_step3(const ushort* __restrict__ xsrc, int tstride, int tloc,
                           const ushort* __restrict__ Wih,
                           const ushort* __restrict__ Whh,
                           const ushort* __restrict__ h_prev,
                           ushort* __restrict__ h_next,
                           float* __restrict__ c,
                           const float* __restrict__ b_ih,
                           const float* __restrict__ b_hh) {
    __shared__ char smem[131072];
    __shared__ float bias_lds[64];

    const int tid  = threadIdx.x;
    const int lane = tid & 63;
    const int w    = tid >> 6;
    const int g    = w >> 1;
    const int ab   = w & 1;

    const int B   = blockIdx.x;
    const int xcd  = B & 7, slot = B >> 3;
    const int jt   = xcd * 8 + (slot >> 2);
    const int bt   = slot & 3;
    const int b0   = bt * 64;

    if (tid < 64) {
        int gcol = (tid >> 4) * 1024 + jt * 16 + (tid & 15);
        bias_lds[tid] = b_ih[gcol] + b_hh[gcol];
    }

    f32x4 acc[4][2] = {};

    auto STAGE = [&](int buf, int it) {
        const int k0 = (g * 6 + it) << 6;
        char* base = smem + g * 32768 + buf * 16384 + ab * 8192;
        if (ab == 0) {
            if (k0 < Dd) {
                #pragma unroll
                for (int q = 0; q < 8; ++q) {
                    int r  = q * 8 + (lane >> 3);
                    int cs = (lane & 7) ^ (r & 7);
                    const ushort* gp = xsrc + ((size_t)(b0 + r) * tstride + tloc) * Dd + k0 + cs * 8;
                    gload16(gp, base + q * 1024);
                }
            } else {
                #pragma unroll
                for (int q = 0; q < 8; ++q) {
                    int r  = q * 8 + (lane >> 3);
                    int cs = (lane & 7) ^ (r & 7);
                    const ushort* gp = h_prev + (size_t)(b0 + r) * Hh + (k0 - Dd) + cs * 8;
                    gload16(gp, base + q * 1024);
                }
            }
        } else {
            #pragma unroll
            for (int q = 0; q < 8; ++q) {
                int col = q * 8 + (lane >> 3);
                int cs  = (lane & 7) ^ (col & 7);
                int grow = (col >> 4) * 1024 + jt * 16 + (col & 15);
                const ushort* gp = (k0 < Dd)
                    ? (Wih + (size_t)grow * Dd + k0 + cs * 8)
                    : (Whh + (size_t)grow * Hh + (k0 - Dd) + cs * 8);
                gload16(gp, base + q * 1024);
            }
        }
    };
    auto COMPUTE = [&](int buf) {
        const char* Ab = smem + g * 32768 + buf * 16384;
        const char* Bb = Ab + 8192;
        #pragma unroll
        for (int ks = 0; ks < 2; ++ks) {
            const int kc = (ks << 2) + (lane >> 4);
            s16x8 a[4], bb[2];
            #pragma unroll
            for (int m = 0; m < 4; ++m) {
                int row = (m << 4) + (lane & 15);
                a[m] = *(const s16x8*)(Ab + row * 128 + ((kc ^ (row & 7)) << 4));
            }
            #pragma unroll
            for (int n = 0; n < 2; ++n) {
                int col = (ab << 5) + (n << 4) + (lane & 15);
                bb[n] = *(const s16x8*)(Bb + col * 128 + ((kc ^ (col & 7)) << 4));
            }
            #pragma unroll
            for (int m = 0; m < 4; ++m)
                #pragma unroll
                for (int n = 0; n < 2; ++n)
                    acc[m][n] = __builtin_amdgcn_mfma_f32_16x16x32_bf16(a[m], bb[n], acc[m][n], 0, 0, 0);
        }
    };

    STAGE(0, 0);
    __syncthreads();
    #pragma unroll
    for (int it = 0; it < 6; ++it) {
        if (it < 5) STAGE((it + 1) & 1, it + 1);
        COMPUTE(it & 1);
        __syncthreads();
    }

    float* bw = (float*)smem + g * (64 * 68);
    #pragma unroll
    for (int m = 0; m < 4; ++m)
        #pragma unroll
        for (int n = 0; n < 2; ++n)
            #pragma unroll
            for (int j = 0; j < 4; ++j) {
                int row = (m << 4) + ((lane >> 4) << 2) + j;
                int col = (ab << 5) + (n << 4) + (lane & 15);
                bw[row * 68 + col] = acc[m][n][j];
            }
    __syncthreads();

    const float* bufs = (const float*)smem;
    #pragma unroll
    for (int u = 0; u < 2; ++u) {
        int cell = tid * 2 + u;
        int row  = cell >> 4;
        int cv   = cell & 15;
        float gi = 0.f, gf = 0.f, gg = 0.f, go = 0.f;
        #pragma unroll
        for (int p = 0; p < 4; ++p) {
            const float* bb = bufs + p * (64 * 68) + row * 68;
            gi += bb[cv]; gf += bb[16 + cv]; gg += bb[32 + cv]; go += bb[48 + cv];
        }
        gi += bias_lds[cv];      gf += bias_lds[16 + cv];
        gg += bias_lds[32 + cv]; go += bias_lds[48 + cv];
        float i_ = sigf(gi), f_ = sigf(gf), g_ = tanhfast(gg), o_ = sigf(go);
        int gcol = jt * 16 + cv;
        size_t cidx = (size_t)(b0 + row) * Hh + gcol;
        float cn = f_ * c[cidx] + i_ * g_;
        c[cidx] = cn;
        h_next[cidx] = f2bf(o_ * tanhfast(cn));
    }
}

// ---------------- T4 fallback (proven round-0) ----------------
__launch_bounds__(256)
__global__ void lstm_step_fused(const float* __restrict__ x,
                          const ushort* __restrict__ Wih,
                          const ushort* __restrict__ Whh,
                          const float* __restrict__ b_ih,
                          const float* __restrict__ b_hh,
                          const ushort* __restrict__ h_prev,
                          ushort* __restrict__ h_next,
                          float* __restrict__ c,
                          int t) {
    __shared__ ushort At[64 * 64];
    __shared__ ushort Bt[64 * 64];
    __shared__ float gates[64 * 72];

    const int tid  = threadIdx.x;
    const int lane = tid & 63;
    const int wid  = tid >> 6;
    const int wr   = wid >> 1;
    const int wc   = wid & 1;
    const int bt   = blockIdx.x >> 6;
    const int jt   = blockIdx.x & 63;
    const int b0   = bt * 64;
    const int j0   = jt * 16;

    f32x4 acc[2][2] = {};

    auto mfma_tile = [&]() {
        #pragma unroll
        for (int ks = 0; ks < 2; ++ks) {
            const int kc = (ks << 2) + (lane >> 4);
            s16x8 a[2], bfr[2];
            #pragma unroll
            for (int m = 0; m < 2; ++m) {
                int row = wr * 32 + m * 16 + (lane & 15);
                a[m] = *(const s16x8*)&At[row * 64 + ((kc ^ (row & 7)) << 3)];
            }
            #pragma unroll
            for (int n = 0; n < 2; ++n) {
                int col = wc * 32 + n * 16 + (lane & 15);
                bfr[n] = *(const s16x8*)&Bt[col * 64 + ((kc ^ (col & 7)) << 3)];
            }
            #pragma unroll
            for (int m = 0; m < 2; ++m)
                #pragma unroll
                for (int n = 0; n < 2; ++n)
                    acc[m][n] = __builtin_amdgcn_mfma_f32_16x16x32_bf16(a[m], bfr[n], acc[m][n], 0, 0, 0);
        }
    };

    for (int kb = 0; kb < Dd; kb += 64) {
        __syncthreads();
        #pragma unroll
        for (int it = 0; it < 4; ++it) {
            int idx = tid + it * 256;
            int row = idx >> 4;
            int k   = (idx & 15) * 4;
            const float4 v = *(const float4*)&x[(size_t)(b0 + row) * (Tlen * Dd) + (size_t)t * Dd + kb + k];
            ushort4 o;
            o.x = f2bf(v.x); o.y = f2bf(v.y); o.z = f2bf(v.z); o.w = f2bf(v.w);
            int dst = row * 64 + (((k >> 3) ^ (row & 7)) << 3) + (k & 7);
            *(ushort4*)&At[dst] = o;
        }
        #pragma unroll
        for (int it = 0; it < 2; ++it) {
            int idx = tid + it * 256;
            int col = idx >> 3;
            int kc  = idx & 7;
            int grow = ((col >> 4) << 10) + j0 + (col & 15);
            uint4 v = *(const uint4*)&Wih[(size_t)grow * Dd + kb + kc * 8];
            *(uint4*)&Bt[col * 64 + ((kc ^ (col & 7)) << 3)] = v;
        }
        __syncthreads();
        mfma_tile();
    }
    for (int kb = 0; kb < Hh; kb += 64) {
        __syncthreads();
        #pragma unroll
        for (int it = 0; it < 2; ++it) {
            int idx = tid + it * 256;
            int row = idx >> 3;
            int kc  = idx & 7;
            uint4 v = *(const uint4*)&h_prev[(size_t)(b0 + row) * Hh + kb + kc * 8];
            *(uint4*)&At[row * 64 + ((kc ^ (row & 7)) << 3)] = v;
        }
        #pragma unroll
        for (int it = 0; it < 2; ++it) {
            int idx = tid + it * 256;
            int col = idx >> 3;
            int kc  = idx & 7;
            int grow = ((col >> 4) << 10) + j0 + (col & 15);
            uint4 v = *(const uint4*)&Whh[(size_t)grow * Hh + kb + kc * 8];
            *(uint4*)&Bt[col * 64 + ((kc ^ (col & 7)) << 3)] = v;
        }
        __syncthreads();
        mfma_tile();
    }

    #pragma unroll
    for (int m = 0; m < 2; ++m)
        #pragma unroll
        for (int n = 0; n < 2; ++n)
            #pragma unroll
            for (int j = 0; j < 4; ++j) {
                int row = wr * 32 + m * 16 + ((lane >> 4) << 2) + j;
                int col = wc * 32 + n * 16 + (lane & 15);
                gates[row * 72 + col] = acc[m][n][j];
            }
    __syncthreads();

    #pragma unroll
    for (int it = 0; it < 4; ++it) {
        int idx = tid + it * 256;
        int row = idx >> 4;
        int cc  = idx & 15;
        int gcol = j0 + cc;
        float gi = gates[row * 72 + cc]      + b_ih[gcol]          + b_hh[gcol];
        float gf = gates[row * 72 + 16 + cc] + b_ih[Hh + gcol]     + b_hh[Hh + gcol];
        float gg = gates[row * 72 + 32 + cc] + b_ih[2 * Hh + gcol] + b_hh[2 * Hh + gcol];
        float go = gates[row * 72 + 48 + cc] + b_ih[3 * Hh + gcol] + b_hh[3 * Hh + gcol];
        float i_ = sigf(gi);
        float f_ = sigf(gf);
        float g_ = tanhfast(gg);
        float o_ = sigf(go);
        size_t cidx = (size_t)(b0 + row) * Hh + gcol;
        float cn = f_ * c[cidx] + i_ * g_;
        c[cidx] = cn;
        float hn = o_ * tanhfast(cn);
        h_next[cidx] = f2bf(hn);
    }
}

// ---------------- FC head ----------------
__global__ void fc_kernel(const ushort* __restrict__ h,
                          const float* __restrict__ Wfc,
                          const float* __restrict__ bfc,
                          float* __restrict__ out) {
    int b = blockIdx.x;
    int w = threadIdx.x >> 6;
    int lane = threadIdx.x & 63;
    float s = 0.f;
    for (int k = lane; k < Hh; k += 64)
        s += bf2f(h[(size_t)b * Hh + k]) * Wfc[w * Hh + k];
    #pragma unroll
    for (int off = 32; off; off >>= 1) s += __shfl_down(s, off);
    if (lane == 0) out[b * NOUT + w] = sigf(s + bfc[w]);
}

// ================= LAUNCH =================

extern "C" void kernel_launch(void* const* d_in, const int* in_sizes, int n_in,
                              void* d_out, int out_size, void* d_ws, size_t ws_size,
                              hipStream_t stream) {
    const float* x    = (const float*)d_in[0];
    const float* W_ih = (const float*)d_in[1];
    const float* W_hh = (const float*)d_in[2];
    const float* b_ih = (const float*)d_in[3];
    const float* b_hh = (const float*)d_in[4];
    const float* W_fc = (const float*)d_in[5];
    const float* b_fc = (const float*)d_in[6];
    float* out = (float*)d_out;
    char* ws = (char*)d_ws;

    // ws layout:
    //   [0, 1 MB)    h ping-pong bf16 [2][256][1024]
    //   [1, 2 MB)    c fp32 [256][1024]
    //   [2, 6 MB)    W_ih bf16 [4096][512]
    //   [6, 14 MB)   W_hh bf16 [4096][1024]
    //   [14 MB, ..)  T1: x_bf (128 MB) + xp fp32 CH=8 (34 MB) = 175 MB (proven r12; CH>8 thrashes L3)
    //                T2: xp fp32 ring 2 x 32 MB = 78 MB (proven r11)
    //                T3: x bf16 chunks 2 x 2 MB (proven r4)
    ushort* h_buf  = (ushort*)ws;
    float*  c_ws   = (float*)(ws + (1ull << 20));
    ushort* wih_bf = (ushort*)(ws + (2ull << 20));
    ushort* whh_bf = (ushort*)(ws + (6ull << 20));
    char*   x_ext  = ws + (14ull << 20);

    const size_t FIXED  = 14ull << 20;
    const size_t XFULL  = (size_t)Bsz * Tlen * Dd * 2;         // 128 MB
    const size_t XP8    = (size_t)8 * Bsz * G4;                // elems
    const size_t XCHUNK = (size_t)Bsz * 8 * Dd * 2;            // 2 MB
    const size_t NEED_T1 = FIXED + XFULL + XP8 * 4;            // 175 MB (proven)
    const size_t NEED_T2 = FIXED + 2 * XP8 * 4;                // 78 MB (proven)

    init_kernel<<<256, 256, 0, stream>>>((uint4*)h_buf, (uint4*)c_ws);
    cvt_kernel<<<(G4 * Dd / 4) / 256, 256, 0, stream>>>((const float4*)W_ih, (ushort4*)wih_bf, G4 * Dd / 4);
    cvt_kernel<<<(G4 * Hh / 4) / 256, 256, 0, stream>>>((const float4*)W_hh, (ushort4*)whh_bf, G4 * Hh / 4);

    if (ws_size >= NEED_T1) {
        // T1: proven r12 path (CH=8; larger CH thrashes L3 per r14)
        ushort* x_bf = (ushort*)x_ext;
        float*  xpb  = (float*)(x_ext + XFULL);
        const int n4 = BT * Dd / 4;
        cvt_kernel<<<n4 / 256, 256, 0, stream>>>((const float4*)x, (ushort4*)x_bf, n4);
        for (int t = 0; t < Tlen; ++t) {
            if ((t & 7) == 0)
                xproj_chunk_bf<<<512, 256, 0, stream>>>(x_bf, wih_bf, b_ih, b_hh, xpb, t);
            const ushort* hp = h_buf + (size_t)(t & 1) * Bsz * Hh;
            ushort*       hn = h_buf + (size_t)((t + 1) & 1) * Bsz * Hh;
            lstm_step9<float><<<256, 512, 0, stream>>>(xpb, t & 7, whh_bf, hp, hn, c_ws);
        }
    } else if (ws_size >= NEED_T2) {
        // T2: proven r11 path (5331 us)
        float* xpb0 = (float*)x_ext;
        float* xpb1 = xpb0 + XP8;
        for (int t = 0; t < Tlen; ++t) {
            float* xpb = ((t >> 3) & 1) ? xpb1 : xpb0;
            if ((t & 7) == 0)
                xproj_chunk<float><<<512, 256, 0, stream>>>(x, wih_bf, b_ih, b_hh, xpb, t);
            const ushort* hp = h_buf + (size_t)(t & 1) * Bsz * Hh;
            ushort*       hn = h_buf + (size_t)((t + 1) & 1) * Bsz * Hh;
            lstm_step9<float><<<256, 512, 0, stream>>>(xpb, t & 7, whh_bf, hp, hn, c_ws);
        }
    } else if (ws_size >= FIXED + 2 * XCHUNK) {
        // T3: r4 chunked path (proven 5618 us)
        ushort* xchunk = (ushort*)x_ext;
        for (int t = 0; t < Tlen; ++t) {
            if ((t & 7) == 0) {
                ushort* dst = xchunk + (size_t)((t >> 3) & 1) * (Bsz * 8 * Dd);
                cvt_xchunk<<<512, 256, 0, stream>>>(x, dst, t);
            }
            const ushort* xb = xchunk + (size_t)((t >> 3) & 1) * (Bsz * 8 * Dd);
            const ushort* hp = h_buf + (size_t)(t & 1) * Bsz * Hh;
            ushort*       hn = h_buf + (size_t)((t + 1) & 1) * Bsz * Hh;
            lstm_step3<<<256, 512, 0, stream>>>(xb, 8, t & 7, wih_bf, whh_bf,
                                                hp, hn, c_ws, b_ih, b_hh);
        }
    } else {
        // T4: proven round-0 fallback
        for (int t = 0; t < Tlen; ++t) {
            const ushort* hp = h_buf + (size_t)(t & 1) * Bsz * Hh;
            ushort*       hn = h_buf + (size_t)((t + 1) & 1) * Bsz * Hh;
            lstm_step_fused<<<256, 256, 0, stream>>>(x, wih_bf, whh_bf, b_ih, b_hh, hp, hn, c_ws, t);
        }
    }
    // 512 steps (even) -> final h in buffer 0
    fc_kernel<<<256, 512, 0, stream>>>(h_buf, W_fc, b_fc, out);
}

// Round 16
// 5033.653 us; speedup vs baseline: 1.0650x; 1.0259x over previous
//
#include <hip/hip_runtime.h>
#include <hip/hip_bf16.h>

#define Bsz 256
#define Tlen 512
#define Dd 512
#define Hh 1024
#define G4 4096
#define NOUT 8
#define BT (Bsz * Tlen)

typedef short s16x8 __attribute__((ext_vector_type(8)));
typedef unsigned short u16x8 __attribute__((ext_vector_type(8)));
typedef float f32x4 __attribute__((ext_vector_type(4)));

__device__ __forceinline__ ushort f2bf(float f) {
    union { float f; uint u; } v; v.f = f;
    uint u = v.u;
    uint r = u + 0x7FFFu + ((u >> 16) & 1u);   // round-to-nearest-even
    return (ushort)(r >> 16);
}
__device__ __forceinline__ float bf2f(ushort u) {
    union { uint u; float f; } v; v.u = ((uint)u) << 16; return v.f;
}
__device__ __forceinline__ float sigf(float x) { return 1.f / (1.f + __expf(-x)); }
__device__ __forceinline__ float tanhfast(float x) {
    float ax = fabsf(x);
    float e = __expf(-2.f * ax);
    float t = (1.f - e) / (1.f + e);
    return copysignf(t, x);
}
__device__ __forceinline__ void gload16(const void* g, void* l) {
    __builtin_amdgcn_global_load_lds(
        (const __attribute__((address_space(1))) uint*)g,
        (__attribute__((address_space(3))) uint*)l, 16, 0, 0);
}
// xp element access (bf16 or fp32 tier)
__device__ __forceinline__ void xp_store(ushort* p, float v) { *p = f2bf(v); }
__device__ __forceinline__ void xp_store(float* p, float v) { *p = v; }
__device__ __forceinline__ float xp_load(const ushort* p) { return bf2f(*p); }
__device__ __forceinline__ float xp_load(const float* p) { return *p; }

// ---------------- init: zero h0 (bf16, buffer 0) and c (fp32) ----------------
__global__ void init_kernel(uint4* __restrict__ h0, uint4* __restrict__ c) {
    int i = blockIdx.x * 256 + threadIdx.x;       // 65536 threads
    uint4 z = make_uint4(0u, 0u, 0u, 0u);
    c[i] = z;                                     // 1 MB
    if (i < 32768) h0[i] = z;                     // 512 KB
}

// ---------------- fp32 -> bf16 convert (layout-preserving) ----------------
__global__ void cvt_kernel(const float4* __restrict__ src, ushort4* __restrict__ dst, int n4) {
    int i = blockIdx.x * 256 + threadIdx.x;
    if (i >= n4) return;
    float4 v = src[i];
    ushort4 o;
    o.x = f2bf(v.x); o.y = f2bf(v.y); o.z = f2bf(v.z); o.w = f2bf(v.w);
    dst[i] = o;
}

// ---------------- chunk convert (fallback T3): x[:, t0..t0+7, :] -> [256][8][512] bf16 ----
__global__ void cvt_xchunk(const float* __restrict__ x, ushort* __restrict__ dst, int t0) {
    int gid = blockIdx.x * 256 + threadIdx.x;     // 131072 units of 8 elems
    int k8  = gid & 63;
    int tl  = (gid >> 6) & 7;
    int row = gid >> 9;                           // 0..255
    const float* s = x + ((size_t)row * Tlen + t0 + tl) * Dd + k8 * 8;
    float4 v0 = *(const float4*)s;
    float4 v1 = *(const float4*)(s + 4);
    u16x8 o;
    o[0]=f2bf(v0.x); o[1]=f2bf(v0.y); o[2]=f2bf(v0.z); o[3]=f2bf(v0.w);
    o[4]=f2bf(v1.x); o[5]=f2bf(v1.y); o[6]=f2bf(v1.z); o[7]=f2bf(v1.w);
    *(u16x8*)(dst + ((size_t)row * 8 + tl) * Dd + k8 * 8) = o;
}

// ---------------- x_proj chunk GEMM, all-gload16, 8 steps per launch ----------------
// xp[tl][b][g] = xbf[b, t0+tl, :] . Wih[g, :] + b_ih[g] + b_hh[g]   (XT = bf16 or fp32)
// M = 2048 (grow = b*8+tl), N = 4096, K = 512. Tile 128x128, 256 thr
// (4 waves of 64x64), BK=64, dbuf, both operands via gload16 (pre-swizzled src).
template <typename XT>
__launch_bounds__(256)
__global__ void xproj_chunk_bf(const ushort* __restrict__ xbf,
                               const ushort* __restrict__ Wih,
                               const float* __restrict__ b_ih,
                               const float* __restrict__ b_hh,
                               XT* __restrict__ xp, int t0) {
    __shared__ ushort As[2][128 * 64];
    __shared__ ushort Bs[2][128 * 64];
    const int tid  = threadIdx.x;
    const int lane = tid & 63;
    const int wid  = tid >> 6;
    const int wr   = wid >> 1;
    const int wc   = wid & 1;
    const int mt   = blockIdx.x >> 5;   // 0..15
    const int nt   = blockIdx.x & 31;   // 0..31
    const int m0   = mt * 128;
    const int n0   = nt * 128;

    f32x4 acc[4][4] = {};

    auto stage = [&](int buf, int kb) {
        const int k0 = kb << 6;
        #pragma unroll
        for (int ii = 0; ii < 4; ++ii) {
            const int inst = (wid << 2) + ii;   // 0..15
            const int r0 = inst << 3;
            const int r  = r0 + (lane >> 3);
            const int sw = ((lane & 7) ^ (r & 7)) << 3;
            const int grow = m0 + r;            // b = grow>>3, tl = grow&7
            gload16(&xbf[((size_t)(grow >> 3) * Tlen + t0 + (grow & 7)) * Dd + k0 + sw],
                    &As[buf][r0 * 64]);
            gload16(&Wih[(size_t)(n0 + r) * Dd + k0 + sw], &Bs[buf][r0 * 64]);
        }
    };
    auto compute = [&](int buf) {
        #pragma unroll
        for (int ks = 0; ks < 2; ++ks) {
            const int kc = (ks << 2) + (lane >> 4);
            s16x8 a[4], b[4];
            #pragma unroll
            for (int m = 0; m < 4; ++m) {
                int row = (wr << 6) + (m << 4) + (lane & 15);
                a[m] = *(const s16x8*)&As[buf][row * 64 + ((kc ^ (row & 7)) << 3)];
            }
            #pragma unroll
            for (int n = 0; n < 4; ++n) {
                int col = (wc << 6) + (n << 4) + (lane & 15);
                b[n] = *(const s16x8*)&Bs[buf][col * 64 + ((kc ^ (col & 7)) << 3)];
            }
            #pragma unroll
            for (int m = 0; m < 4; ++m)
                #pragma unroll
                for (int n = 0; n < 4; ++n)
                    acc[m][n] = __builtin_amdgcn_mfma_f32_16x16x32_bf16(a[m], b[n], acc[m][n], 0, 0, 0);
        }
    };

    stage(0, 0);
    __syncthreads();
    for (int kb = 0; kb < 8; ++kb) {
        if (kb < 7) stage((kb + 1) & 1, kb + 1);
        compute(kb & 1);
        __syncthreads();
    }

    float bias[4];
    #pragma unroll
    for (int n = 0; n < 4; ++n) {
        int gcol = n0 + (wc << 6) + (n << 4) + (lane & 15);
        bias[n] = b_ih[gcol] + b_hh[gcol];
    }
    #pragma unroll
    for (int m = 0; m < 4; ++m)
        #pragma unroll
        for (int n = 0; n < 4; ++n)
            #pragma unroll
            for (int j = 0; j < 4; ++j) {
                int grow = m0 + (wr << 6) + (m << 4) + ((lane >> 4) << 2) + j;
                int gcol = n0 + (wc << 6) + (n << 4) + (lane & 15);
                int b_ = grow >> 3, tl = grow & 7;
                xp_store(&xp[((size_t)tl * Bsz + b_) * G4 + gcol], acc[m][n][j] + bias[n]);
            }
}

// ---------------- x_proj chunk GEMM (T2, proven r11): A from fp32 x ----------------
template <typename XT>
__launch_bounds__(256)
__global__ void xproj_chunk(const float* __restrict__ x,
                            const ushort* __restrict__ Wih,
                            const float* __restrict__ b_ih,
                            const float* __restrict__ b_hh,
                            XT* __restrict__ xp, int t0) {
    __shared__ ushort As[2][128 * 64];
    __shared__ ushort Bs[2][128 * 64];
    const int tid  = threadIdx.x;
    const int lane = tid & 63;
    const int wid  = tid >> 6;
    const int wr   = wid >> 1;
    const int wc   = wid & 1;
    const int mt   = blockIdx.x >> 5;   // 0..15
    const int nt   = blockIdx.x & 31;   // 0..31
    const int m0   = mt * 128;
    const int n0   = nt * 128;

    f32x4 acc[4][4] = {};

    auto stageA = [&](int buf, int kb) {
        const int k0 = kb << 6;
        #pragma unroll
        for (int it = 0; it < 8; ++it) {
            int idx = tid + (it << 8);          // 0..2047
            int row = idx >> 4;                 // 0..127
            int k   = (idx & 15) << 2;          // 0..60
            int grow = m0 + row;                // b = grow>>3, tl = grow&7
            const float4 v = *(const float4*)&x[((size_t)(grow >> 3) * Tlen + t0 + (grow & 7)) * Dd + k0 + k];
            ushort4 o;
            o.x = f2bf(v.x); o.y = f2bf(v.y); o.z = f2bf(v.z); o.w = f2bf(v.w);
            int dst = (row << 6) + (((k >> 3) ^ (row & 7)) << 3) + (k & 7);
            *(ushort4*)&As[buf][dst] = o;
        }
    };
    auto stageB = [&](int buf, int kb) {
        const int k0 = kb << 6;
        #pragma unroll
        for (int ii = 0; ii < 4; ++ii) {
            const int inst = (wid << 2) + ii;   // 0..15
            const int r0 = inst << 3;
            const int r  = r0 + (lane >> 3);
            const int sw = ((lane & 7) ^ (r & 7)) << 3;
            gload16(&Wih[(size_t)(n0 + r) * Dd + k0 + sw], &Bs[buf][r0 * 64]);
        }
    };
    auto compute = [&](int buf) {
        #pragma unroll
        for (int ks = 0; ks < 2; ++ks) {
            const int kc = (ks << 2) + (lane >> 4);
            s16x8 a[4], b[4];
            #pragma unroll
            for (int m = 0; m < 4; ++m) {
                int row = (wr << 6) + (m << 4) + (lane & 15);
                a[m] = *(const s16x8*)&As[buf][row * 64 + ((kc ^ (row & 7)) << 3)];
            }
            #pragma unroll
            for (int n = 0; n < 4; ++n) {
                int col = (wc << 6) + (n << 4) + (lane & 15);
                b[n] = *(const s16x8*)&Bs[buf][col * 64 + ((kc ^ (col & 7)) << 3)];
            }
            #pragma unroll
            for (int m = 0; m < 4; ++m)
                #pragma unroll
                for (int n = 0; n < 4; ++n)
                    acc[m][n] = __builtin_amdgcn_mfma_f32_16x16x32_bf16(a[m], b[n], acc[m][n], 0, 0, 0);
        }
    };

    stageB(0, 0); stageA(0, 0);
    __syncthreads();
    for (int kb = 0; kb < 8; ++kb) {
        if (kb < 7) { stageB((kb + 1) & 1, kb + 1); stageA((kb + 1) & 1, kb + 1); }
        compute(kb & 1);
        __syncthreads();
    }

    float bias[4];
    #pragma unroll
    for (int n = 0; n < 4; ++n) {
        int gcol = n0 + (wc << 6) + (n << 4) + (lane & 15);
        bias[n] = b_ih[gcol] + b_hh[gcol];
    }
    #pragma unroll
    for (int m = 0; m < 4; ++m)
        #pragma unroll
        for (int n = 0; n < 4; ++n)
            #pragma unroll
            for (int j = 0; j < 4; ++j) {
                int grow = m0 + (wr << 6) + (m << 4) + ((lane >> 4) << 2) + j;
                int gcol = n0 + (wc << 6) + (n << 4) + (lane & 15);
                int b_ = grow >> 3, tl = grow & 7;
                xp_store(&xp[((size_t)tl * Bsz + b_) * G4 + gcol], acc[m][n][j] + bias[n]);
            }
}

// ---------------- LSTM step, K=1024 recurrent only (r15 structure, proven) ----------------
template <typename XT>
__launch_bounds__(512, 2)
__global__ void lstm_step9(const XT* __restrict__ xp,    // [8][256][4096] chunk incl. biases
                           int tl,
                           const ushort* __restrict__ Whh,   // bf16 [4096][1024]
                           const ushort* __restrict__ h_prev,// bf16 [256][1024]
                           ushort* __restrict__ h_next,
                           float* __restrict__ c) {          // fp32 [256][1024]
    __shared__ char smem[131072];

    const int tid  = threadIdx.x;
    const int lane = tid & 63;
    const int w    = tid >> 6;
    const int g    = w >> 1;         // K-group 0..3
    const int ab   = w & 1;
    const int B    = blockIdx.x;
    const int xcd  = B & 7, slot = B >> 3;
    const int jt   = xcd * 8 + (slot >> 2);
    const int bt   = slot & 3;
    const int b0   = bt * 64;

    auto STAGE = [&](int buf, int it) {
        const int k0 = (g << 8) + (it << 6);
        char* base = smem + g * 32768 + buf * 16384 + ab * 8192;
        if (ab == 0) {
            #pragma unroll
            for (int q = 0; q < 8; ++q) {
                int r  = q * 8 + (lane >> 3);
                int cs = (lane & 7) ^ (r & 7);
                gload16(h_prev + (size_t)(b0 + r) * Hh + k0 + cs * 8, base + q * 1024);
            }
        } else {
            #pragma unroll
            for (int q = 0; q < 8; ++q) {
                int col = q * 8 + (lane >> 3);
                int cs  = (lane & 7) ^ (col & 7);
                int grow = ((col >> 4) << 10) + (jt << 4) + (col & 15);
                gload16(Whh + (size_t)grow * Hh + k0 + cs * 8, base + q * 1024);
            }
        }
    };

    // ---- critical-path staging first: round 0 loads enter the VMEM queue
    // before the epilogue prefetch (which isn't needed for ~5 us).
    STAGE(0, 0);

    // ---- epilogue prefetch (hidden under the K-loop) ----
    const int erow = tid >> 3;            // 0..63
    const int ecv  = (tid * 2) & 15;      // even
    const size_t cbase = (size_t)(b0 + erow) * Hh + (jt << 4) + ecv;
    const float c0 = c[cbase], c1 = c[cbase + 1];
    const XT* xpr = xp + ((size_t)tl * Bsz + b0 + erow) * G4 + (jt << 4) + ecv;
    float xg[4][2];
    #pragma unroll
    for (int gi = 0; gi < 4; ++gi) {
        xg[gi][0] = xp_load(xpr + gi * Hh);
        xg[gi][1] = xp_load(xpr + gi * Hh + 1);
    }

    f32x4 acc[4][2] = {};

    auto COMPUTE = [&](int buf) {
        const char* Ab = smem + g * 32768 + buf * 16384;
        const char* Bb = Ab + 8192;
        #pragma unroll
        for (int ks = 0; ks < 2; ++ks) {
            const int kc = (ks << 2) + (lane >> 4);
            s16x8 a[4], bb[2];
            #pragma unroll
            for (int m = 0; m < 4; ++m) {
                int row = (m << 4) + (lane & 15);
                a[m] = *(const s16x8*)(Ab + row * 128 + ((kc ^ (row & 7)) << 4));
            }
            #pragma unroll
            for (int n = 0; n < 2; ++n) {
                int col = (ab << 5) + (n << 4) + (lane & 15);
                bb[n] = *(const s16x8*)(Bb + col * 128 + ((kc ^ (col & 7)) << 4));
            }
            #pragma unroll
            for (int m = 0; m < 4; ++m)
                #pragma unroll
                for (int n = 0; n < 2; ++n)
                    acc[m][n] = __builtin_amdgcn_mfma_f32_16x16x32_bf16(a[m], bb[n], acc[m][n], 0, 0, 0);
        }
    };

    __syncthreads();
    #pragma unroll
    for (int it = 0; it < 4; ++it) {
        if (it < 3) STAGE((it + 1) & 1, it + 1);
        COMPUTE(it & 1);
        __syncthreads();
    }

    // ---- partials: group g -> LDS ----
    float* bw = (float*)smem + g * (64 * 68);
    #pragma unroll
    for (int m = 0; m < 4; ++m)
        #pragma unroll
        for (int n = 0; n < 2; ++n)
            #pragma unroll
            for (int j = 0; j < 4; ++j) {
                int row = (m << 4) + ((lane >> 4) << 2) + j;
                int col = (ab << 5) + (n << 4) + (lane & 15);
                bw[row * 68 + col] = acc[m][n][j];
            }
    __syncthreads();

    // ---- reduce 4 partials + activations + cell update ----
    const float* bufs = (const float*)smem;
    #pragma unroll
    for (int u = 0; u < 2; ++u) {
        const int cv = ecv + u;
        float gi = xg[0][u], gf = xg[1][u], gg = xg[2][u], go = xg[3][u];
        #pragma unroll
        for (int p = 0; p < 4; ++p) {
            const float* bb = bufs + p * (64 * 68) + erow * 68;
            gi += bb[cv]; gf += bb[16 + cv]; gg += bb[32 + cv]; go += bb[48 + cv];
        }
        float i_ = sigf(gi), f_ = sigf(gf), g_ = tanhfast(gg), o_ = sigf(go);
        float cn = f_ * (u ? c1 : c0) + i_ * g_;
        c[cbase + u] = cn;
        h_next[cbase + u] = f2bf(o_ * tanhfast(cn));
    }
}

// ---------------- r4 step kernel (fallback T3, proven 5618 us) ----------------
__launch_bounds__(512, 2)
__global__ void lstm_step3(const ushort* __restrict__ xsrc, int tstride, int tloc,
                           const ushort* __restrict__ Wih,
                           const ushort* __restrict__ Whh,
                           const ushort* __restrict__ h_prev,
                           ushort* __restrict__ h_next,
                           float* __restrict__ c,
                           const float* __restrict__ b_ih,
                           const float* __restrict__ b_hh) {
    __shared__ char smem[131072];
    __shared__ float bias_lds[64];

    const int tid  = threadIdx.x;
    const int lane = tid & 63;
    const int w    = tid >> 6;
    const int g    = w >> 1;
    const int ab   = w & 1;

    const int B   = blockIdx.x;
    const int xcd  = B & 7, slot = B >> 3;
    const int jt   = xcd * 8 + (slot >> 2);
    const int bt   = slot & 3;
    const int b0   = bt * 64;

    if (tid < 64) {
        int gcol = (tid >> 4) * 1024 + jt * 16 + (tid & 15);
        bias_lds[tid] = b_ih[gcol] + b_hh[gcol];
    }

    f32x4 acc[4][2] = {};

    auto STAGE = [&](int buf, int it) {
        const int k0 = (g * 6 + it) << 6;
        char* base = smem + g * 32768 + buf * 16384 + ab * 8192;
        if (ab == 0) {
            if (k0 < Dd) {
                #pragma unroll
                for (int q = 0; q < 8; ++q) {
                    int r  = q * 8 + (lane >> 3);
                    int cs = (lane & 7) ^ (r & 7);
                    const ushort* gp = xsrc + ((size_t)(b0 + r) * tstride + tloc) * Dd + k0 + cs * 8;
                    gload16(gp, base + q * 1024);
                }
            } else {
                #pragma unroll
                for (int q = 0; q < 8; ++q) {
                    int r  = q * 8 + (lane >> 3);
                    int cs = (lane & 7) ^ (r & 7);
                    const ushort* gp = h_prev + (size_t)(b0 + r) * Hh + (k0 - Dd) + cs * 8;
                    gload16(gp, base + q * 1024);
                }
            }
        } else {
            #pragma unroll
            for (int q = 0; q < 8; ++q) {
                int col = q * 8 + (lane >> 3);
                int cs  = (lane & 7) ^ (col & 7);
                int grow = (col >> 4) * 1024 + jt * 16 + (col & 15);
                const ushort* gp = (k0 < Dd)
                    ? (Wih + (size_t)grow * Dd + k0 + cs * 8)
                    : (Whh + (size_t)grow * Hh + (k0 - Dd) + cs * 8);
                gload16(gp, base + q * 1024);
            }
        }
    };
    auto COMPUTE = [&](int buf) {
        const char* Ab = smem + g * 32768 + buf * 16384;
        const char* Bb = Ab + 8192;
        #pragma unroll
        for (int ks = 0; ks < 2; ++ks) {
            const int kc = (ks << 2) + (lane >> 4);
            s16x8 a[4], bb[2];
            #pragma unroll
            for (int m = 0; m < 4; ++m) {
                int row = (m << 4) + (lane & 15);
                a[m] = *(const s16x8*)(Ab + row * 128 + ((kc ^ (row & 7)) << 4));
            }
            #pragma unroll
            for (int n = 0; n < 2; ++n) {
                int col = (ab << 5) + (n << 4) + (lane & 15);
                bb[n] = *(const s16x8*)(Bb + col * 128 + ((kc ^ (col & 7)) << 4));
            }
            #pragma unroll
            for (int m = 0; m < 4; ++m)
                #pragma unroll
                for (int n = 0; n < 2; ++n)
                    acc[m][n] = __builtin_amdgcn_mfma_f32_16x16x32_bf16(a[m], bb[n], acc[m][n], 0, 0, 0);
        }
    };

    STAGE(0, 0);
    __syncthreads();
    #pragma unroll
    for (int it = 0; it < 6; ++it) {
        if (it < 5) STAGE((it + 1) & 1, it + 1);
        COMPUTE(it & 1);
        __syncthreads();
    }

    float* bw = (float*)smem + g * (64 * 68);
    #pragma unroll
    for (int m = 0; m < 4; ++m)
        #pragma unroll
        for (int n = 0; n < 2; ++n)
            #pragma unroll
            for (int j = 0; j < 4; ++j) {
                int row = (m << 4) + ((lane >> 4) << 2) + j;
                int col = (ab << 5) + (n << 4) + (lane & 15);
                bw[row * 68 + col] = acc[m][n][j];
            }
    __syncthreads();

    const float* bufs = (const float*)smem;
    #pragma unroll
    for (int u = 0; u < 2; ++u) {
        int cell = tid * 2 + u;
        int row  = cell >> 4;
        int cv   = cell & 15;
        float gi = 0.f, gf = 0.f, gg = 0.f, go = 0.f;
        #pragma unroll
        for (int p = 0; p < 4; ++p) {
            const float* bb = bufs + p * (64 * 68) + row * 68;
            gi += bb[cv]; gf += bb[16 + cv]; gg += bb[32 + cv]; go += bb[48 + cv];
        }
        gi += bias_lds[cv];      gf += bias_lds[16 + cv];
        gg += bias_lds[32 + cv]; go += bias_lds[48 + cv];
        float i_ = sigf(gi), f_ = sigf(gf), g_ = tanhfast(gg), o_ = sigf(go);
        int gcol = jt * 16 + cv;
        size_t cidx = (size_t)(b0 + row) * Hh + gcol;
        float cn = f_ * c[cidx] + i_ * g_;
        c[cidx] = cn;
        h_next[cidx] = f2bf(o_ * tanhfast(cn));
    }
}

// ---------------- T4 fallback (proven round-0) ----------------
__launch_bounds__(256)
__global__ void lstm_step_fused(const float* __restrict__ x,
                          const ushort* __restrict__ Wih,
                          const ushort* __restrict__ Whh,
                          const float* __restrict__ b_ih,
                          const float* __restrict__ b_hh,
                          const ushort* __restrict__ h_prev,
                          ushort* __restrict__ h_next,
                          float* __restrict__ c,
                          int t) {
    __shared__ ushort At[64 * 64];
    __shared__ ushort Bt[64 * 64];
    __shared__ float gates[64 * 72];

    const int tid  = threadIdx.x;
    const int lane = tid & 63;
    const int wid  = tid >> 6;
    const int wr   = wid >> 1;
    const int wc   = wid & 1;
    const int bt   = blockIdx.x >> 6;
    const int jt   = blockIdx.x & 63;
    const int b0   = bt * 64;
    const int j0   = jt * 16;

    f32x4 acc[2][2] = {};

    auto mfma_tile = [&]() {
        #pragma unroll
        for (int ks = 0; ks < 2; ++ks) {
            const int kc = (ks << 2) + (lane >> 4);
            s16x8 a[2], bfr[2];
            #pragma unroll
            for (int m = 0; m < 2; ++m) {
                int row = wr * 32 + m * 16 + (lane & 15);
                a[m] = *(const s16x8*)&At[row * 64 + ((kc ^ (row & 7)) << 3)];
            }
            #pragma unroll
            for (int n = 0; n < 2; ++n) {
                int col = wc * 32 + n * 16 + (lane & 15);
                bfr[n] = *(const s16x8*)&Bt[col * 64 + ((kc ^ (col & 7)) << 3)];
            }
            #pragma unroll
            for (int m = 0; m < 2; ++m)
                #pragma unroll
                for (int n = 0; n < 2; ++n)
                    acc[m][n] = __builtin_amdgcn_mfma_f32_16x16x32_bf16(a[m], bfr[n], acc[m][n], 0, 0, 0);
        }
    };

    for (int kb = 0; kb < Dd; kb += 64) {
        __syncthreads();
        #pragma unroll
        for (int it = 0; it < 4; ++it) {
            int idx = tid + it * 256;
            int row = idx >> 4;
            int k   = (idx & 15) * 4;
            const float4 v = *(const float4*)&x[(size_t)(b0 + row) * (Tlen * Dd) + (size_t)t * Dd + kb + k];
            ushort4 o;
            o.x = f2bf(v.x); o.y = f2bf(v.y); o.z = f2bf(v.z); o.w = f2bf(v.w);
            int dst = row * 64 + (((k >> 3) ^ (row & 7)) << 3) + (k & 7);
            *(ushort4*)&At[dst] = o;
        }
        #pragma unroll
        for (int it = 0; it < 2; ++it) {
            int idx = tid + it * 256;
            int col = idx >> 3;
            int kc  = idx & 7;
            int grow = ((col >> 4) << 10) + j0 + (col & 15);
            uint4 v = *(const uint4*)&Wih[(size_t)grow * Dd + kb + kc * 8];
            *(uint4*)&Bt[col * 64 + ((kc ^ (col & 7)) << 3)] = v;
        }
        __syncthreads();
        mfma_tile();
    }
    for (int kb = 0; kb < Hh; kb += 64) {
        __syncthreads();
        #pragma unroll
        for (int it = 0; it < 2; ++it) {
            int idx = tid + it * 256;
            int row = idx >> 3;
            int kc  = idx & 7;
            uint4 v = *(const uint4*)&h_prev[(size_t)(b0 + row) * Hh + kb + kc * 8];
            *(uint4*)&At[row * 64 + ((kc ^ (row & 7)) << 3)] = v;
        }
        #pragma unroll
        for (int it = 0; it < 2; ++it) {
            int idx = tid + it * 256;
            int col = idx >> 3;
            int kc  = idx & 7;
            int grow = ((col >> 4) << 10) + j0 + (col & 15);
            uint4 v = *(const uint4*)&Whh[(size_t)grow * Hh + kb + kc * 8];
            *(uint4*)&Bt[col * 64 + ((kc ^ (col & 7)) << 3)] = v;
        }
        __syncthreads();
        mfma_tile();
    }

    #pragma unroll
    for (int m = 0; m < 2; ++m)
        #pragma unroll
        for (int n = 0; n < 2; ++n)
            #pragma unroll
            for (int j = 0; j < 4; ++j) {
                int row = wr * 32 + m * 16 + ((lane >> 4) << 2) + j;
                int col = wc * 32 + n * 16 + (lane & 15);
                gates[row * 72 + col] = acc[m][n][j];
            }
    __syncthreads();

    #pragma unroll
    for (int it = 0; it < 4; ++it) {
        int idx = tid + it * 256;
        int row = idx >> 4;
        int cc  = idx & 15;
        int gcol = j0 + cc;
        float gi = gates[row * 72 + cc]      + b_ih[gcol]          + b_hh[gcol];
        float gf = gates[row * 72 + 16 + cc] + b_ih[Hh + gcol]     + b_hh[Hh + gcol];
        float gg = gates[row * 72 + 32 + cc] + b_ih[2 * Hh + gcol] + b_hh[2 * Hh + gcol];
        float go = gates[row * 72 + 48 + cc] + b_ih[3 * Hh + gcol] + b_hh[3 * Hh + gcol];
        float i_ = sigf(gi);
        float f_ = sigf(gf);
        float g_ = tanhfast(gg);
        float o_ = sigf(go);
        size_t cidx = (size_t)(b0 + row) * Hh + gcol;
        float cn = f_ * c[cidx] + i_ * g_;
        c[cidx] = cn;
        float hn = o_ * tanhfast(cn);
        h_next[cidx] = f2bf(hn);
    }
}

// ---------------- FC head ----------------
__global__ void fc_kernel(const ushort* __restrict__ h,
                          const float* __restrict__ Wfc,
                          const float* __restrict__ bfc,
                          float* __restrict__ out) {
    int b = blockIdx.x;
    int w = threadIdx.x >> 6;
    int lane = threadIdx.x & 63;
    float s = 0.f;
    for (int k = lane; k < Hh; k += 64)
        s += bf2f(h[(size_t)b * Hh + k]) * Wfc[w * Hh + k];
    #pragma unroll
    for (int off = 32; off; off >>= 1) s += __shfl_down(s, off);
    if (lane == 0) out[b * NOUT + w] = sigf(s + bfc[w]);
}

// ================= LAUNCH =================

extern "C" void kernel_launch(void* const* d_in, const int* in_sizes, int n_in,
                              void* d_out, int out_size, void* d_ws, size_t ws_size,
                              hipStream_t stream) {
    const float* x    = (const float*)d_in[0];
    const float* W_ih = (const float*)d_in[1];
    const float* W_hh = (const float*)d_in[2];
    const float* b_ih = (const float*)d_in[3];
    const float* b_hh = (const float*)d_in[4];
    const float* W_fc = (const float*)d_in[5];
    const float* b_fc = (const float*)d_in[6];
    float* out = (float*)d_out;
    char* ws = (char*)d_ws;

    // ws layout:
    //   [0, 1 MB)    h ping-pong bf16 [2][256][1024]
    //   [1, 2 MB)    c fp32 [256][1024]
    //   [2, 6 MB)    W_ih bf16 [4096][512]
    //   [6, 14 MB)   W_hh bf16 [4096][1024]
    //   [14 MB, ..)  T1: x_bf (128 MB) + xp bf16 CH=8 (17 MB) -- gated at 175 MB (proven)
    //                T2: xp fp32 ring 2 x 32 MB = 78 MB (proven r11)
    //                T3: x bf16 chunks 2 x 2 MB (proven r4)
    ushort* h_buf  = (ushort*)ws;
    float*  c_ws   = (float*)(ws + (1ull << 20));
    ushort* wih_bf = (ushort*)(ws + (2ull << 20));
    ushort* whh_bf = (ushort*)(ws + (6ull << 20));
    char*   x_ext  = ws + (14ull << 20);

    const size_t FIXED  = 14ull << 20;
    const size_t XFULL  = (size_t)Bsz * Tlen * Dd * 2;         // 128 MB
    const size_t XP8    = (size_t)8 * Bsz * G4;                // elems
    const size_t XCHUNK = (size_t)Bsz * 8 * Dd * 2;            // 2 MB
    const size_t NEED_T1 = FIXED + XFULL + XP8 * 4;            // 175 MB gate (proven available)
    const size_t NEED_T2 = FIXED + 2 * XP8 * 4;                // 78 MB (proven)

    init_kernel<<<256, 256, 0, stream>>>((uint4*)h_buf, (uint4*)c_ws);
    cvt_kernel<<<(G4 * Dd / 4) / 256, 256, 0, stream>>>((const float4*)W_ih, (ushort4*)wih_bf, G4 * Dd / 4);
    cvt_kernel<<<(G4 * Hh / 4) / 256, 256, 0, stream>>>((const float4*)W_hh, (ushort4*)whh_bf, G4 * Hh / 4);

    if (ws_size >= NEED_T1) {
        // T1: r15 structure with bf16 xp (halves GEMM writes + epilogue reads)
        ushort* x_bf = (ushort*)x_ext;
        ushort* xpb  = (ushort*)(x_ext + XFULL);
        const int n4 = BT * Dd / 4;
        cvt_kernel<<<n4 / 256, 256, 0, stream>>>((const float4*)x, (ushort4*)x_bf, n4);
        for (int t = 0; t < Tlen; ++t) {
            if ((t & 7) == 0)
                xproj_chunk_bf<ushort><<<512, 256, 0, stream>>>(x_bf, wih_bf, b_ih, b_hh, xpb, t);
            const ushort* hp = h_buf + (size_t)(t & 1) * Bsz * Hh;
            ushort*       hn = h_buf + (size_t)((t + 1) & 1) * Bsz * Hh;
            lstm_step9<ushort><<<256, 512, 0, stream>>>(xpb, t & 7, whh_bf, hp, hn, c_ws);
        }
    } else if (ws_size >= NEED_T2) {
        // T2: proven r11 path (5331 us, fp32 xp)
        float* xpb0 = (float*)x_ext;
        float* xpb1 = xpb0 + XP8;
        for (int t = 0; t < Tlen; ++t) {
            float* xpb = ((t >> 3) & 1) ? xpb1 : xpb0;
            if ((t & 7) == 0)
                xproj_chunk<float><<<512, 256, 0, stream>>>(x, wih_bf, b_ih, b_hh, xpb, t);
            const ushort* hp = h_buf + (size_t)(t & 1) * Bsz * Hh;
            ushort*       hn = h_buf + (size_t)((t + 1) & 1) * Bsz * Hh;
            lstm_step9<float><<<256, 512, 0, stream>>>(xpb, t & 7, whh_bf, hp, hn, c_ws);
        }
    } else if (ws_size >= FIXED + 2 * XCHUNK) {
        // T3: r4 chunked path (proven 5618 us)
        ushort* xchunk = (ushort*)x_ext;
        for (int t = 0; t < Tlen; ++t) {
            if ((t & 7) == 0) {
                ushort* dst = xchunk + (size_t)((t >> 3) & 1) * (Bsz * 8 * Dd);
                cvt_xchunk<<<512, 256, 0, stream>>>(x, dst, t);
            }
            const ushort* xb = xchunk + (size_t)((t >> 3) & 1) * (Bsz * 8 * Dd);
            const ushort* hp = h_buf + (size_t)(t & 1) * Bsz * Hh;
            ushort*       hn = h_buf + (size_t)((t + 1) & 1) * Bsz * Hh;
            lstm_step3<<<256, 512, 0, stream>>>(xb, 8, t & 7, wih_bf, whh_bf,
                                                hp, hn, c_ws, b_ih, b_hh);
        }
    } else {
        // T4: proven round-0 fallback
        for (int t = 0; t < Tlen; ++t) {
            const ushort* hp = h_buf + (size_t)(t & 1) * Bsz * Hh;
            ushort*       hn = h_buf + (size_t)((t + 1) & 1) * Bsz * Hh;
            lstm_step_fused<<<256, 256, 0, stream>>>(x, wih_bf, whh_bf, b_ih, b_hh, hp, hn, c_ws, t);
        }
    }
    // 512 steps (even) -> final h in buffer 0
    fc_kernel<<<256, 512, 0, stream>>>(h_buf, W_fc, b_fc, out);
}